// Round 17
// baseline (238.062 us; speedup 1.0000x reference)
//
#include <hip/hip_runtime.h>
#include <cstdint>
#include <cstddef>
#include <math.h>

typedef _Float16 half8 __attribute__((ext_vector_type(8)));
typedef _Float16 half4 __attribute__((ext_vector_type(4)));
typedef float f32x4 __attribute__((ext_vector_type(4)));
typedef float f32x16 __attribute__((ext_vector_type(16)));
typedef unsigned int uint2v __attribute__((ext_vector_type(2)));

#define NB  2
#define NT  2048
#define NC  1024
#define NH  16
#define ND  64

__device__ __forceinline__ void gload_lds16(const _Float16* g, _Float16* l) {
  __builtin_amdgcn_global_load_lds((const __attribute__((address_space(1))) void*)g,
                                   (__attribute__((address_space(3))) void*)l, 16, 0, 0);
}

// v_permlane32_swap_b32: r[0]={a.lo,b.lo}, r[1]={a.hi,b.hi}.
// NEVER call with a==b (same SSA value) — regalloc coalescing makes it a self-swap.
__device__ __forceinline__ uint2v plswap(unsigned a, unsigned b) {
  return __builtin_amdgcn_permlane32_swap(a, b, false, false);
}

// ---------------- convert x -> fp16 ----------------
__global__ void k_cvt_x(const float* __restrict__ x, _Float16* __restrict__ xh) {
  const int n4 = (4096 * 1024) / 4;
  int i = blockIdx.x * 256 + threadIdx.x;
  for (; i < n4; i += 2048 * 256) {
    float4 v = ((const float4*)x)[i];
    half4 h = { (_Float16)v.x, (_Float16)v.y, (_Float16)v.z, (_Float16)v.w };
    ((half4*)xh)[i] = h;
  }
}

// ------------- transpose+convert W (1024x1024) -> WT[n][k] fp16 -------------
__global__ void k_tw(const float* __restrict__ W0, const float* __restrict__ W1,
                     const float* __restrict__ W2, const float* __restrict__ W3,
                     _Float16* __restrict__ WT) {
  const float* W = (blockIdx.z == 0) ? W0 : (blockIdx.z == 1) ? W1 : (blockIdx.z == 2) ? W2 : W3;
  _Float16* out = WT + ((size_t)blockIdx.z << 20);
  __shared__ float t[32][33];
  const int x0 = blockIdx.x * 32;  // n
  const int y0 = blockIdx.y * 32;  // k
  const int tx = threadIdx.x, ty = threadIdx.y;  // (32,8)
#pragma unroll
  for (int r = 0; r < 4; ++r)
    t[ty + 8 * r][tx] = W[(size_t)(y0 + ty + 8 * r) * 1024 + x0 + tx];
  __syncthreads();
#pragma unroll
  for (int r = 0; r < 4; ++r)
    out[(size_t)(x0 + ty + 8 * r) * 1024 + y0 + tx] = (_Float16)t[tx][ty + 8 * r];
}

// ---------------- shared GEMM mainloop: C(128x128) = A(128xK) * B^T(128xK) ----------------
__device__ __forceinline__ void gemm_mainloop(const _Float16* __restrict__ A,
                                              const _Float16* __restrict__ Bmat,
                                              int m0, int n0,
                                              _Float16* As, _Float16* Bs,
                                              f32x4 acc[4][4]) {
  const int tid = threadIdx.x;
  const int lane = tid & 63;
  const int wid = tid >> 6;
  const int wm = wid >> 1, wn = wid & 1;
  const int c16 = lane & 15, rg = lane >> 4;

  for (int k0 = 0; k0 < 1024; k0 += 64) {
    __syncthreads();
#pragma unroll
    for (int i = 0; i < 4; ++i) {
      int e = (i * 256 + tid) * 8;       // element index within 128x64 tile
      int row = e >> 6;                  // 0..127
      int chunk = (e & 63) >> 3;         // 0..7 (16B chunk)
      int scol = ((chunk ^ (row & 7)) << 3);  // source-side swizzle (involution)
      gload_lds16(A + (size_t)(m0 + row) * 1024 + k0 + scol,
                  As + (size_t)(i * 256 + (wid << 6)) * 8);
      gload_lds16(Bmat + (size_t)(n0 + row) * 1024 + k0 + scol,
                  Bs + (size_t)(i * 256 + (wid << 6)) * 8);
    }
    __syncthreads();
#pragma unroll
    for (int kk = 0; kk < 2; ++kk) {
      half8 af[4], bfr[4];
#pragma unroll
      for (int mi = 0; mi < 4; ++mi) {
        int row = (wm << 6) + (mi << 4) + c16;
        int chunk = (kk << 2) + rg;
        af[mi] = *(const half8*)&As[(row << 6) + ((chunk ^ (row & 7)) << 3)];
      }
#pragma unroll
      for (int ni = 0; ni < 4; ++ni) {
        int row = (wn << 6) + (ni << 4) + c16;
        int chunk = (kk << 2) + rg;
        bfr[ni] = *(const half8*)&Bs[(row << 6) + ((chunk ^ (row & 7)) << 3)];
      }
#pragma unroll
      for (int mi = 0; mi < 4; ++mi)
#pragma unroll
        for (int ni = 0; ni < 4; ++ni)
          acc[mi][ni] = __builtin_amdgcn_mfma_f32_16x16x32_f16(af[mi], bfr[ni], acc[mi][ni], 0, 0, 0);
    }
  }
}

// ---------------- QKV GEMM + bias + RoPE + scatter ----------------
// Q -> [bh][t][d] scaled by (1/8)*log2(e) (exp2-domain softmax); K -> [bh][t][d];
// V -> transposed [bh][d][t]
__global__ __launch_bounds__(256, 2) void k_qkv(const _Float16* __restrict__ xh,
                                                const _Float16* __restrict__ WT,
                                                const float* __restrict__ bq,
                                                const float* __restrict__ bk,
                                                const float* __restrict__ bv,
                                                _Float16* __restrict__ Qh,
                                                _Float16* __restrict__ Kh,
                                                _Float16* __restrict__ VT) {
  __shared__ __align__(16) _Float16 As[128 * 64];
  __shared__ __align__(16) _Float16 Bs[128 * 64];
  f32x4 acc[4][4];
#pragma unroll
  for (int i = 0; i < 4; ++i)
#pragma unroll
    for (int j = 0; j < 4; ++j) acc[i][j] = (f32x4){0.f, 0.f, 0.f, 0.f};

  const int m0 = blockIdx.y * 128;
  const int ng = blockIdx.x * 128;   // 0..3071
  const int p = ng >> 10;            // 0=q,1=k,2=v
  const int n0 = ng & 1023;
  gemm_mainloop(xh, WT + ((size_t)p << 20), m0, n0, As, Bs, acc);

  const int tid = threadIdx.x, lane = tid & 63, wid = tid >> 6;
  const int wm = wid >> 1, wn = wid & 1, c16 = lane & 15, rg = lane >> 4;
  const float* bias = (p == 0) ? bq : (p == 1) ? bk : bv;
  const int nw = n0 + (wn << 6);
  const int head = nw >> 6;          // wave's 64-col strip is exactly one head
  float bi[4];
#pragma unroll
  for (int ni = 0; ni < 4; ++ni) bi[ni] = bias[nw + (ni << 4) + c16];

  if (p == 2) {  // V: store transposed [bh][d][t], vectorized half4 over t
#pragma unroll
    for (int mi = 0; mi < 4; ++mi) {
      int m = m0 + (wm << 6) + (mi << 4) + (rg << 2);
      int b = m >> 11, t0 = m & 2047;
#pragma unroll
      for (int ni = 0; ni < 4; ++ni) {
        half4 hv;
#pragma unroll
        for (int r = 0; r < 4; ++r) hv[r] = (_Float16)(acc[mi][ni][r] + bi[ni]);
        size_t base = ((size_t)(b * NH + head) * ND + (ni << 4) + c16) * NT + t0;
        *(half4*)&VT[base] = hv;
      }
    }
    return;
  }

  _Float16* Out = (p == 0) ? Qh : Kh;
  // inv_freq[c16] = 10000^(-c16/16) = 2^(-c16 * log2(10000)/16)  (accurate exp2)
  const float invf = exp2f((float)c16 * -0.8304820237218405f);
  // Q scale: (1/sqrt(64)) * log2(e)  -> S from MFMA is directly in exp2 domain
  const float qscale = (p == 0) ? 0.18033688011112042f : 1.0f;

#pragma unroll
  for (int mi = 0; mi < 4; ++mi) {
#pragma unroll
    for (int r = 0; r < 4; ++r) {
      int m = m0 + (wm << 6) + (mi << 4) + (rg << 2) + r;
      int b = m >> 11, t = m & 2047;
      float v0 = acc[mi][0][r] + bi[0];
      float v1 = acc[mi][1][r] + bi[1];
      float v2 = acc[mi][2][r] + bi[2];
      float v3 = acc[mi][3][r] + bi[3];
      {  // RoPE on d<32: pair (d, d+16)
        float th = (float)t * invf;
        float sn, cs;
        sincosf(th, &sn, &cs);   // theta reaches 2047 rad: needs libm range reduction
        float nx = v0 * cs - v1 * sn;
        v1 = v1 * cs + v0 * sn;
        v0 = nx;
      }
      size_t base = ((size_t)(b * NH + head) * NT + t) * ND;
      Out[base + 0 + c16]  = (_Float16)(v0 * qscale);
      Out[base + 16 + c16] = (_Float16)(v1 * qscale);
      Out[base + 32 + c16] = (_Float16)(v2 * qscale);
      Out[base + 48 + c16] = (_Float16)(v3 * qscale);
    }
  }
}

// ------ flash attention: 64-row tiles, 2 waves, K staged in LDS via global_load_lds ------
// 1024 blocks x 128 thr; block = (bh, pt): rows [pt*64, pt*64+64); wave w owns rows
// +32w. Shared kv walk (tiles of 32), K tile (4KB) double-buffered in LDS with
// source-side XOR swizzle (dest linear for gload_lds; read applies same XOR).
// One barrier per tile; STAGE(it+1) issues before BODY(it) -> latency hidden.
// V direct-global (consumed late). No kv-split -> no merge. Zero staging VGPRs.
__global__ __launch_bounds__(128, 4) void k_attn(const _Float16* __restrict__ Qh,
                                                 const _Float16* __restrict__ Kh,
                                                 const _Float16* __restrict__ VT,
                                                 _Float16* __restrict__ Oh) {
  const int lin = blockIdx.x;            // 0..1023
  const int xcd = lin & 7;
  const int slot = lin >> 3;             // 0..127 within XCD
  const int bh = (xcd << 2) | (slot & 3);// 4 bh per XCD -> K+V 2MB in per-XCD L2
  const int k32 = slot >> 2;             // 0..31
  const int pt = (k32 < 16) ? (31 - k32) : (k32 - 16);  // LPT: long tiles first

  const int tid = threadIdx.x, lane = tid & 63, wid = tid >> 6;  // wid 0..1
  const int q31 = lane & 31, hi = lane >> 5;
  const size_t hb = (size_t)bh * NT * ND;
  const _Float16* Qp = Qh + hb;
  const _Float16* Kp = Kh + hb;
  const _Float16* Vp = VT + hb;
  const int b = bh >> 4, h = bh & 15;

  __shared__ __align__(16) _Float16 Ks[2][32 * 64];   // 8 KB dbuf

  const int q0w = (pt << 6) + (wid << 5);  // this wave's 32 q-rows
  const int qg = q0w + q31;
  const int niter = 2 * (pt + 1);          // kv tiles of 32 (block-shared walk)

  half8 qf[4];
#pragma unroll
  for (int c = 0; c < 4; ++c)
    qf[c] = *(const half8*)&Qp[(size_t)qg * ND + (c << 4) + (hi << 3)];

  f32x16 oacc0, oacc1;
#pragma unroll
  for (int r = 0; r < 16; ++r) { oacc0[r] = 0.f; oacc1[r] = 0.f; }
  float lacc[8];
#pragma unroll
  for (int r = 0; r < 8; ++r) lacc[r] = 0.f;
  float m = -INFINITY;

  half8 vfr[4];

  // cooperative K staging: 4 gload_lds per tile, wave w issues instrs {2w, 2w+1}.
  // instr i covers rows i*8..i*8+7; lane l -> row r=i*8+(l>>3), chunk c=l&7 (16B).
  // LDS slot [r][c] receives global chunk c^(r&7)  (source-side swizzle).
  const int sg_r = (lane >> 3);          // 0..7 within instr
  const int sg_c = lane & 7;
#define STAGEK(buf, ktv) do {                                                   \
    _Pragma("unroll")                                                           \
    for (int i2 = 0; i2 < 2; ++i2) {                                            \
      int i_ = wid * 2 + i2;                                                    \
      int r_ = i_ * 8 + sg_r;                                                   \
      gload_lds16(Kp + (size_t)((ktv) + r_) * ND + ((sg_c ^ (r_ & 7)) << 3),    \
                  &Ks[buf][i_ * 512]);                                          \
    } } while (0)

#define LOADV(ktv) do {                                                         \
    _Pragma("unroll")                                                           \
    for (int dh = 0; dh < 2; ++dh)                                              \
      _Pragma("unroll")                                                         \
      for (int ks = 0; ks < 2; ++ks)                                            \
        vfr[dh * 2 + ks] = *(const half8*)&Vp[(size_t)((dh << 5) + q31) * NT    \
                                              + (ktv) + (ks << 4) + (hi << 3)]; \
  } while (0)

#define BODY(buf, ktc) do {                                                     \
    half8 kA[4];                                                                \
    _Pragma("unroll")                                                           \
    for (int c = 0; c < 4; ++c)                                                 \
      kA[c] = *(const half8*)&Ks[buf][(q31 << 6) + ((((c << 1) + hi) ^ (q31 & 7)) << 3)]; \
    f32x16 s;                                                                   \
    _Pragma("unroll")                                                           \
    for (int r = 0; r < 16; ++r) s[r] = 0.f;                                    \
    __builtin_amdgcn_s_setprio(1);                                              \
    _Pragma("unroll")                                                           \
    for (int c = 0; c < 4; ++c)                                                 \
      s = __builtin_amdgcn_mfma_f32_32x32x16_f16(kA[c], qf[c], s, 0, 0, 0);     \
    __builtin_amdgcn_s_setprio(0);                                              \
    if ((ktc) + 31 > q0w) {  /* causal mask: partial tile for this wave */      \
      int rel = qg - (ktc) - (hi << 2);                                         \
      _Pragma("unroll")                                                         \
      for (int r = 0; r < 16; ++r) {                                            \
        int crow = (r & 3) + ((r >> 2) << 3);                                   \
        if (crow > rel) s[r] = -INFINITY;                                       \
      }                                                                         \
    }                                                                           \
    float t8[8];                                                                \
    _Pragma("unroll")                                                           \
    for (int r = 0; r < 8; ++r) t8[r] = fmaxf(s[r], s[r + 8]);                  \
    _Pragma("unroll")                                                           \
    for (int r = 0; r < 4; ++r) t8[r] = fmaxf(t8[r], t8[r + 4]);                \
    float pm = fmaxf(fmaxf(t8[0], t8[1]), fmaxf(t8[2], t8[3]));                 \
    pm = fmaxf(pm, __shfl_xor(pm, 32));                                         \
    if (!__all(pm <= m + 11.54f)) {  /* defer-max, THR=8*log2e */               \
      float mn = fmaxf(m, pm);                                                  \
      float corr = exp2f(m - mn);                                               \
      m = mn;                                                                   \
      _Pragma("unroll")                                                         \
      for (int r = 0; r < 16; ++r) { oacc0[r] *= corr; oacc1[r] *= corr; }      \
      _Pragma("unroll")                                                         \
      for (int r = 0; r < 8; ++r) lacc[r] *= corr;                              \
    }                                                                           \
    _Pragma("unroll")                                                           \
    for (int r = 0; r < 16; ++r) s[r] = exp2f(s[r] - m);                        \
    _Pragma("unroll")                                                           \
    for (int r = 0; r < 8; ++r) lacc[r] += s[r] + s[r + 8];                     \
    unsigned pw0 = __builtin_bit_cast(unsigned, __builtin_amdgcn_cvt_pkrtz(s[0], s[1]));   \
    unsigned pw1 = __builtin_bit_cast(unsigned, __builtin_amdgcn_cvt_pkrtz(s[2], s[3]));   \
    unsigned pw2 = __builtin_bit_cast(unsigned, __builtin_amdgcn_cvt_pkrtz(s[4], s[5]));   \
    unsigned pw3 = __builtin_bit_cast(unsigned, __builtin_amdgcn_cvt_pkrtz(s[6], s[7]));   \
    unsigned pw4 = __builtin_bit_cast(unsigned, __builtin_amdgcn_cvt_pkrtz(s[8], s[9]));   \
    unsigned pw5 = __builtin_bit_cast(unsigned, __builtin_amdgcn_cvt_pkrtz(s[10], s[11])); \
    unsigned pw6 = __builtin_bit_cast(unsigned, __builtin_amdgcn_cvt_pkrtz(s[12], s[13])); \
    unsigned pw7 = __builtin_bit_cast(unsigned, __builtin_amdgcn_cvt_pkrtz(s[14], s[15])); \
    uint2v rA0 = plswap(pw0, pw2);                                              \
    uint2v rA1 = plswap(pw1, pw3);                                              \
    uint2v rB0 = plswap(pw4, pw6);                                              \
    uint2v rB1 = plswap(pw5, pw7);                                              \
    uint4 ua, ub;                                                               \
    ua.x = rA0[0]; ua.y = rA1[0]; ua.z = rA0[1]; ua.w = rA1[1];                 \
    ub.x = rB0[0]; ub.y = rB1[0]; ub.z = rB0[1]; ub.w = rB1[1];                 \
    half8 pa0 = __builtin_bit_cast(half8, ua);                                  \
    half8 pa1 = __builtin_bit_cast(half8, ub);                                  \
    __builtin_amdgcn_s_setprio(1);                                              \
    oacc0 = __builtin_amdgcn_mfma_f32_32x32x16_f16(vfr[0], pa0, oacc0, 0, 0, 0); \
    oacc0 = __builtin_amdgcn_mfma_f32_32x32x16_f16(vfr[1], pa1, oacc0, 0, 0, 0); \
    oacc1 = __builtin_amdgcn_mfma_f32_32x32x16_f16(vfr[2], pa0, oacc1, 0, 0, 0); \
    oacc1 = __builtin_amdgcn_mfma_f32_32x32x16_f16(vfr[3], pa1, oacc1, 0, 0, 0); \
    __builtin_amdgcn_s_setprio(0);                                              \
  } while (0)

  // pipelined kv loop: one barrier per tile; STAGE(it+1) overlaps BODY(it)
  STAGEK(0, 0);
  __syncthreads();
  for (int it = 0; it < niter; ++it) {
    if (it + 1 < niter) STAGEK((it + 1) & 1, (it + 1) << 5);
    __builtin_amdgcn_sched_barrier(0);
    const int kt = it << 5;
    if (kt <= q0w + 31) {   // wave-uniform causal skip (wave 0 tail tile)
      LOADV(kt);
      if ((it & 1) == 0) BODY(0, kt); else BODY(1, kt);
    }
    __syncthreads();
  }
#undef STAGEK
#undef LOADV
#undef BODY

  // per-wave l reduction (in-lane tree + cross-half shfl), direct store
  float l4[4];
#pragma unroll
  for (int r = 0; r < 4; ++r) l4[r] = lacc[r] + lacc[r + 4];
  float ls = (l4[0] + l4[1]) + (l4[2] + l4[3]);
  ls += __shfl_xor(ls, 32);
  float il = 1.f / ls;
  size_t obase = ((size_t)b * NT + qg) * NC + h * ND;
#pragma unroll
  for (int g2 = 0; g2 < 4; ++g2) {
    int d0 = (g2 << 3) + (hi << 2);
    half4 h4, h5;
#pragma unroll
    for (int r = 0; r < 4; ++r) {
      h4[r] = (_Float16)(oacc0[(g2 << 2) + r] * il);
      h5[r] = (_Float16)(oacc1[(g2 << 2) + r] * il);
    }
    *(half4*)&Oh[obase + d0] = h4;
    *(half4*)&Oh[obase + 32 + d0] = h5;
  }
}

// ---------------- output projection GEMM (fp32 out + bias) ----------------
__global__ __launch_bounds__(256, 2) void k_out(const _Float16* __restrict__ Oh,
                                                const _Float16* __restrict__ WoT,
                                                const float* __restrict__ bo,
                                                float* __restrict__ out) {
  __shared__ __align__(16) _Float16 As[128 * 64];
  __shared__ __align__(16) _Float16 Bs[128 * 64];
  f32x4 acc[4][4];
#pragma unroll
  for (int i = 0; i < 4; ++i)
#pragma unroll
    for (int j = 0; j < 4; ++j) acc[i][j] = (f32x4){0.f, 0.f, 0.f, 0.f};

  const int m0 = blockIdx.y * 128;
  const int n0 = blockIdx.x * 128;
  gemm_mainloop(Oh, WoT, m0, n0, As, Bs, acc);

  const int tid = threadIdx.x, lane = tid & 63, wid = tid >> 6;
  const int wm = wid >> 1, wn = wid & 1, c16 = lane & 15, rg = lane >> 4;
  float bi[4];
#pragma unroll
  for (int ni = 0; ni < 4; ++ni) bi[ni] = bo[n0 + (wn << 6) + (ni << 4) + c16];
#pragma unroll
  for (int mi = 0; mi < 4; ++mi) {
#pragma unroll
    for (int r = 0; r < 4; ++r) {
      int m = m0 + (wm << 6) + (mi << 4) + (rg << 2) + r;
#pragma unroll
      for (int ni = 0; ni < 4; ++ni) {
        int n = n0 + (wn << 6) + (ni << 4) + c16;
        out[(size_t)m * NC + n] = acc[mi][ni][r] + bi[ni];
      }
    }
  }
}

extern "C" void kernel_launch(void* const* d_in, const int* in_sizes, int n_in,
                              void* d_out, int out_size, void* d_ws, size_t ws_size,
                              hipStream_t stream) {
  const float* x  = (const float*)d_in[0];
  const float* Wq = (const float*)d_in[1];
  const float* bq = (const float*)d_in[2];
  const float* Wk = (const float*)d_in[3];
  const float* bk = (const float*)d_in[4];
  const float* Wv = (const float*)d_in[5];
  const float* bv = (const float*)d_in[6];
  const float* Wo = (const float*)d_in[7];
  const float* bo = (const float*)d_in[8];
  float* out = (float*)d_out;

  char* ws = (char*)d_ws;
  _Float16* xh = (_Float16*)ws;                       // 8 MB  [4096][1024]
  _Float16* WT = (_Float16*)(ws + (8ull << 20));      // 8 MB  [4][1024][1024] n-major
  _Float16* Qh = (_Float16*)(ws + (16ull << 20));     // 8 MB  [32][2048][64]
  _Float16* Kh = (_Float16*)(ws + (24ull << 20));     // 8 MB  [32][2048][64]
  _Float16* Vt = (_Float16*)(ws + (32ull << 20));     // 8 MB  [32][64][2048] (transposed)
  _Float16* Oh = (_Float16*)(ws + (40ull << 20));     // 8 MB  [4096][1024]

  k_cvt_x<<<2048, 256, 0, stream>>>(x, xh);
  k_tw<<<dim3(32, 32, 4), dim3(32, 8), 0, stream>>>(Wq, Wk, Wv, Wo, WT);
  k_qkv<<<dim3(24, 32), 256, 0, stream>>>(xh, WT, bq, bk, bv, Qh, Kh, Vt);
  k_attn<<<1024, 128, 0, stream>>>(Qh, Kh, Vt, Oh);
  k_out<<<dim3(8, 32), 256, 0, stream>>>(Oh, WT + (3ull << 20), bo, out);
}

// Round 18
// 129.386 us; speedup vs baseline: 1.8399x; 1.8399x over previous
//
#include <hip/hip_runtime.h>
#include <cstdint>
#include <cstddef>
#include <math.h>

typedef _Float16 half8 __attribute__((ext_vector_type(8)));
typedef _Float16 half4 __attribute__((ext_vector_type(4)));
typedef float f32x4 __attribute__((ext_vector_type(4)));
typedef float f32x16 __attribute__((ext_vector_type(16)));
typedef unsigned int uint2v __attribute__((ext_vector_type(2)));

#define NB  2
#define NT  2048
#define NC  1024
#define NH  16
#define ND  64

__device__ __forceinline__ void gload_lds16(const _Float16* g, _Float16* l) {
  __builtin_amdgcn_global_load_lds((const __attribute__((address_space(1))) void*)g,
                                   (__attribute__((address_space(3))) void*)l, 16, 0, 0);
}

// v_permlane32_swap_b32: r[0]={a.lo,b.lo}, r[1]={a.hi,b.hi}.
// NEVER call with a==b (same SSA value) — regalloc coalescing makes it a self-swap.
__device__ __forceinline__ uint2v plswap(unsigned a, unsigned b) {
  return __builtin_amdgcn_permlane32_swap(a, b, false, false);
}

// ---------------- convert x -> fp16 ----------------
__global__ void k_cvt_x(const float* __restrict__ x, _Float16* __restrict__ xh) {
  const int n4 = (4096 * 1024) / 4;
  int i = blockIdx.x * 256 + threadIdx.x;
  for (; i < n4; i += 2048 * 256) {
    float4 v = ((const float4*)x)[i];
    half4 h = { (_Float16)v.x, (_Float16)v.y, (_Float16)v.z, (_Float16)v.w };
    ((half4*)xh)[i] = h;
  }
}

// ------------- transpose+convert W (1024x1024) -> WT[n][k] fp16 -------------
__global__ void k_tw(const float* __restrict__ W0, const float* __restrict__ W1,
                     const float* __restrict__ W2, const float* __restrict__ W3,
                     _Float16* __restrict__ WT) {
  const float* W = (blockIdx.z == 0) ? W0 : (blockIdx.z == 1) ? W1 : (blockIdx.z == 2) ? W2 : W3;
  _Float16* out = WT + ((size_t)blockIdx.z << 20);
  __shared__ float t[32][33];
  const int x0 = blockIdx.x * 32;  // n
  const int y0 = blockIdx.y * 32;  // k
  const int tx = threadIdx.x, ty = threadIdx.y;  // (32,8)
#pragma unroll
  for (int r = 0; r < 4; ++r)
    t[ty + 8 * r][tx] = W[(size_t)(y0 + ty + 8 * r) * 1024 + x0 + tx];
  __syncthreads();
#pragma unroll
  for (int r = 0; r < 4; ++r)
    out[(size_t)(x0 + ty + 8 * r) * 1024 + y0 + tx] = (_Float16)t[tx][ty + 8 * r];
}

// ---------------- shared GEMM mainloop: C(128x128) = A(128xK) * B^T(128xK) ----------------
__device__ __forceinline__ void gemm_mainloop(const _Float16* __restrict__ A,
                                              const _Float16* __restrict__ Bmat,
                                              int m0, int n0,
                                              _Float16* As, _Float16* Bs,
                                              f32x4 acc[4][4]) {
  const int tid = threadIdx.x;
  const int lane = tid & 63;
  const int wid = tid >> 6;
  const int wm = wid >> 1, wn = wid & 1;
  const int c16 = lane & 15, rg = lane >> 4;

  for (int k0 = 0; k0 < 1024; k0 += 64) {
    __syncthreads();
#pragma unroll
    for (int i = 0; i < 4; ++i) {
      int e = (i * 256 + tid) * 8;       // element index within 128x64 tile
      int row = e >> 6;                  // 0..127
      int chunk = (e & 63) >> 3;         // 0..7 (16B chunk)
      int scol = ((chunk ^ (row & 7)) << 3);  // source-side swizzle (involution)
      gload_lds16(A + (size_t)(m0 + row) * 1024 + k0 + scol,
                  As + (size_t)(i * 256 + (wid << 6)) * 8);
      gload_lds16(Bmat + (size_t)(n0 + row) * 1024 + k0 + scol,
                  Bs + (size_t)(i * 256 + (wid << 6)) * 8);
    }
    __syncthreads();
#pragma unroll
    for (int kk = 0; kk < 2; ++kk) {
      half8 af[4], bfr[4];
#pragma unroll
      for (int mi = 0; mi < 4; ++mi) {
        int row = (wm << 6) + (mi << 4) + c16;
        int chunk = (kk << 2) + rg;
        af[mi] = *(const half8*)&As[(row << 6) + ((chunk ^ (row & 7)) << 3)];
      }
#pragma unroll
      for (int ni = 0; ni < 4; ++ni) {
        int row = (wn << 6) + (ni << 4) + c16;
        int chunk = (kk << 2) + rg;
        bfr[ni] = *(const half8*)&Bs[(row << 6) + ((chunk ^ (row & 7)) << 3)];
      }
#pragma unroll
      for (int mi = 0; mi < 4; ++mi)
#pragma unroll
        for (int ni = 0; ni < 4; ++ni)
          acc[mi][ni] = __builtin_amdgcn_mfma_f32_16x16x32_f16(af[mi], bfr[ni], acc[mi][ni], 0, 0, 0);
    }
  }
}

// ---------------- QKV GEMM + bias + RoPE + scatter ----------------
// Q -> [bh][t][d] scaled by (1/8)*log2(e) (exp2-domain softmax); K -> [bh][t][d];
// V -> transposed [bh][d][t]
__global__ __launch_bounds__(256, 2) void k_qkv(const _Float16* __restrict__ xh,
                                                const _Float16* __restrict__ WT,
                                                const float* __restrict__ bq,
                                                const float* __restrict__ bk,
                                                const float* __restrict__ bv,
                                                _Float16* __restrict__ Qh,
                                                _Float16* __restrict__ Kh,
                                                _Float16* __restrict__ VT) {
  __shared__ __align__(16) _Float16 As[128 * 64];
  __shared__ __align__(16) _Float16 Bs[128 * 64];
  f32x4 acc[4][4];
#pragma unroll
  for (int i = 0; i < 4; ++i)
#pragma unroll
    for (int j = 0; j < 4; ++j) acc[i][j] = (f32x4){0.f, 0.f, 0.f, 0.f};

  const int m0 = blockIdx.y * 128;
  const int ng = blockIdx.x * 128;   // 0..3071
  const int p = ng >> 10;            // 0=q,1=k,2=v
  const int n0 = ng & 1023;
  gemm_mainloop(xh, WT + ((size_t)p << 20), m0, n0, As, Bs, acc);

  const int tid = threadIdx.x, lane = tid & 63, wid = tid >> 6;
  const int wm = wid >> 1, wn = wid & 1, c16 = lane & 15, rg = lane >> 4;
  const float* bias = (p == 0) ? bq : (p == 1) ? bk : bv;
  const int nw = n0 + (wn << 6);
  const int head = nw >> 6;          // wave's 64-col strip is exactly one head
  float bi[4];
#pragma unroll
  for (int ni = 0; ni < 4; ++ni) bi[ni] = bias[nw + (ni << 4) + c16];

  if (p == 2) {  // V: store transposed [bh][d][t], vectorized half4 over t
#pragma unroll
    for (int mi = 0; mi < 4; ++mi) {
      int m = m0 + (wm << 6) + (mi << 4) + (rg << 2);
      int b = m >> 11, t0 = m & 2047;
#pragma unroll
      for (int ni = 0; ni < 4; ++ni) {
        half4 hv;
#pragma unroll
        for (int r = 0; r < 4; ++r) hv[r] = (_Float16)(acc[mi][ni][r] + bi[ni]);
        size_t base = ((size_t)(b * NH + head) * ND + (ni << 4) + c16) * NT + t0;
        *(half4*)&VT[base] = hv;
      }
    }
    return;
  }

  _Float16* Out = (p == 0) ? Qh : Kh;
  // inv_freq[c16] = 10000^(-c16/16) = 2^(-c16 * log2(10000)/16)  (accurate exp2)
  const float invf = exp2f((float)c16 * -0.8304820237218405f);
  // Q scale: (1/sqrt(64)) * log2(e)  -> S from MFMA is directly in exp2 domain
  const float qscale = (p == 0) ? 0.18033688011112042f : 1.0f;

#pragma unroll
  for (int mi = 0; mi < 4; ++mi) {
#pragma unroll
    for (int r = 0; r < 4; ++r) {
      int m = m0 + (wm << 6) + (mi << 4) + (rg << 2) + r;
      int b = m >> 11, t = m & 2047;
      float v0 = acc[mi][0][r] + bi[0];
      float v1 = acc[mi][1][r] + bi[1];
      float v2 = acc[mi][2][r] + bi[2];
      float v3 = acc[mi][3][r] + bi[3];
      {  // RoPE on d<32: pair (d, d+16)
        float th = (float)t * invf;
        float sn, cs;
        sincosf(th, &sn, &cs);   // theta reaches 2047 rad: needs libm range reduction
        float nx = v0 * cs - v1 * sn;
        v1 = v1 * cs + v0 * sn;
        v0 = nx;
      }
      size_t base = ((size_t)(b * NH + head) * NT + t) * ND;
      Out[base + 0 + c16]  = (_Float16)(v0 * qscale);
      Out[base + 16 + c16] = (_Float16)(v1 * qscale);
      Out[base + 32 + c16] = (_Float16)(v2 * qscale);
      Out[base + 48 + c16] = (_Float16)(v3 * qscale);
    }
  }
}

// ------ flash attention: 64-row tiles, 4 waves = 2 strips x (kv-lo, kv-hi) ------
// 1024 blocks x 256 thr; block = (bh, t): rows [t*64, t*64+64). Wave wid: strip
// s=wid&1 (32 rows), role=wid>>1 (0 = kv [0,nh2), 1 = kv [nh2,n)); n = 2t+s+1.
// Partials merged per strip via LDS. 16 waves/CU (4/SIMD). Const-sum co-residency:
// rounds get tiles {31-k, k, 23-k, 8+k} (sum 62) so each CU's 4 blocks equalize.
// R13 config (best measured: 77us attn, zero spill at the exact 128-reg cap).
// K issued before V each iter (K consumed first by QK^T).
__global__ __launch_bounds__(256, 4) void k_attn(const _Float16* __restrict__ Qh,
                                                 const _Float16* __restrict__ Kh,
                                                 const _Float16* __restrict__ VT,
                                                 _Float16* __restrict__ Oh) {
  const int lin = blockIdx.x;            // 0..1023
  const int xcd = lin & 7;
  const int slot = lin >> 3;             // 0..127 within XCD
  const int rnd = slot >> 5;             // co-residency round 0..3
  const int pos = slot & 31;
  const int bh = (xcd << 2) | (pos & 3); // 4 bh per XCD -> K+V 2MB in per-XCD L2
  const int k8 = pos >> 2;               // 0..7
  const int t = (rnd == 0) ? (31 - k8) : (rnd == 1) ? k8
              : (rnd == 2) ? (23 - k8) : (8 + k8);   // sums to 62 across rounds

  const int tid = threadIdx.x, lane = tid & 63, wid = tid >> 6;  // wid 0..3
  const int s_strip = wid & 1, role = wid >> 1;
  const int q31 = lane & 31, hi = lane >> 5;
  const size_t hb = (size_t)bh * NT * ND;
  const _Float16* Qp = Qh + hb;
  const _Float16* Kp = Kh + hb;
  const _Float16* Vp = VT + hb;
  const int b = bh >> 4, h = bh & 15;

  __shared__ float Osh[2][32][65];       // hi-role partial O per strip, +1 pad
  __shared__ float msh[2][32], lsh[2][32];

  const int q0w = (t << 6) + (s_strip << 5);  // this wave's 32 q-rows
  const int qg = q0w + q31;
  const int n = 2 * t + s_strip + 1;     // kv iterations (32 kv each) for this strip
  const int nh2 = (n + 1) >> 1;
  int it = role ? nh2 : 0;
  const int itend = role ? n : nh2;

  half8 qf[4];
#pragma unroll
  for (int c = 0; c < 4; ++c)
    qf[c] = *(const half8*)&Qp[(size_t)qg * ND + (c << 4) + (hi << 3)];

  f32x16 oacc0, oacc1;
#pragma unroll
  for (int r = 0; r < 16; ++r) { oacc0[r] = 0.f; oacc1[r] = 0.f; }
  float lacc[8];
#pragma unroll
  for (int r = 0; r < 8; ++r) lacc[r] = 0.f;
  float m = -INFINITY;

  half8 kA[4], vfr[4];

#define LOADK(ktv) do {                                                         \
    const _Float16* kp_ = Kp + (size_t)((ktv) + q31) * ND + (hi << 3);          \
    kA[0] = *(const half8*)(kp_);                                               \
    kA[1] = *(const half8*)(kp_ + 16);                                          \
    kA[2] = *(const half8*)(kp_ + 32);                                          \
    kA[3] = *(const half8*)(kp_ + 48);                                          \
  } while (0)

#define LOADV(ktv) do {                                                         \
    _Pragma("unroll")                                                           \
    for (int dh = 0; dh < 2; ++dh)                                              \
      _Pragma("unroll")                                                         \
      for (int ks = 0; ks < 2; ++ks)                                            \
        vfr[dh * 2 + ks] = *(const half8*)&Vp[(size_t)((dh << 5) + q31) * NT    \
                                              + (ktv) + (ks << 4) + (hi << 3)]; \
  } while (0)

#define BODY(ktc) do {                                                          \
    f32x16 s;                                                                   \
    _Pragma("unroll")                                                           \
    for (int r = 0; r < 16; ++r) s[r] = 0.f;                                    \
    __builtin_amdgcn_s_setprio(1);                                              \
    _Pragma("unroll")                                                           \
    for (int c = 0; c < 4; ++c)                                                 \
      s = __builtin_amdgcn_mfma_f32_32x32x16_f16(kA[c], qf[c], s, 0, 0, 0);     \
    __builtin_amdgcn_s_setprio(0);                                              \
    if ((ktc) + 31 > q0w) {  /* causal mask: only the strip's final iter */     \
      int rel = qg - (ktc) - (hi << 2);                                         \
      _Pragma("unroll")                                                         \
      for (int r = 0; r < 16; ++r) {                                            \
        int crow = (r & 3) + ((r >> 2) << 3);                                   \
        if (crow > rel) s[r] = -INFINITY;                                       \
      }                                                                         \
    }                                                                           \
    /* row max: in-lane tree + cross-half shfl */                               \
    float t8[8];                                                                \
    _Pragma("unroll")                                                           \
    for (int r = 0; r < 8; ++r) t8[r] = fmaxf(s[r], s[r + 8]);                  \
    _Pragma("unroll")                                                           \
    for (int r = 0; r < 4; ++r) t8[r] = fmaxf(t8[r], t8[r + 4]);                \
    float pm = fmaxf(fmaxf(t8[0], t8[1]), fmaxf(t8[2], t8[3]));                 \
    pm = fmaxf(pm, __shfl_xor(pm, 32));                                         \
    if (!__all(pm <= m + 11.54f)) {  /* defer-max, THR=8*log2e */               \
      float mn = fmaxf(m, pm);                                                  \
      float corr = exp2f(m - mn);                                               \
      m = mn;                                                                   \
      _Pragma("unroll")                                                         \
      for (int r = 0; r < 16; ++r) { oacc0[r] *= corr; oacc1[r] *= corr; }      \
      _Pragma("unroll")                                                         \
      for (int r = 0; r < 8; ++r) lacc[r] *= corr;                              \
    }                                                                           \
    _Pragma("unroll")                                                           \
    for (int r = 0; r < 16; ++r) s[r] = exp2f(s[r] - m);                        \
    _Pragma("unroll")                                                           \
    for (int r = 0; r < 8; ++r) lacc[r] += s[r] + s[r + 8];                     \
    /* pack P; plswap(loWord, hiWord): r[0]->frag lo word, r[1]->hi */          \
    unsigned pw0 = __builtin_bit_cast(unsigned, __builtin_amdgcn_cvt_pkrtz(s[0], s[1]));   \
    unsigned pw1 = __builtin_bit_cast(unsigned, __builtin_amdgcn_cvt_pkrtz(s[2], s[3]));   \
    unsigned pw2 = __builtin_bit_cast(unsigned, __builtin_amdgcn_cvt_pkrtz(s[4], s[5]));   \
    unsigned pw3 = __builtin_bit_cast(unsigned, __builtin_amdgcn_cvt_pkrtz(s[6], s[7]));   \
    unsigned pw4 = __builtin_bit_cast(unsigned, __builtin_amdgcn_cvt_pkrtz(s[8], s[9]));   \
    unsigned pw5 = __builtin_bit_cast(unsigned, __builtin_amdgcn_cvt_pkrtz(s[10], s[11])); \
    unsigned pw6 = __builtin_bit_cast(unsigned, __builtin_amdgcn_cvt_pkrtz(s[12], s[13])); \
    unsigned pw7 = __builtin_bit_cast(unsigned, __builtin_amdgcn_cvt_pkrtz(s[14], s[15])); \
    uint2v rA0 = plswap(pw0, pw2);                                              \
    uint2v rA1 = plswap(pw1, pw3);                                              \
    uint2v rB0 = plswap(pw4, pw6);                                              \
    uint2v rB1 = plswap(pw5, pw7);                                              \
    uint4 ua, ub;                                                               \
    ua.x = rA0[0]; ua.y = rA1[0]; ua.z = rA0[1]; ua.w = rA1[1];                 \
    ub.x = rB0[0]; ub.y = rB1[0]; ub.z = rB0[1]; ub.w = rB1[1];                 \
    half8 pa0 = __builtin_bit_cast(half8, ua);                                  \
    half8 pa1 = __builtin_bit_cast(half8, ub);                                  \
    __builtin_amdgcn_s_setprio(1);                                              \
    oacc0 = __builtin_amdgcn_mfma_f32_32x32x16_f16(vfr[0], pa0, oacc0, 0, 0, 0); \
    oacc0 = __builtin_amdgcn_mfma_f32_32x32x16_f16(vfr[1], pa1, oacc0, 0, 0, 0); \
    oacc1 = __builtin_amdgcn_mfma_f32_32x32x16_f16(vfr[2], pa0, oacc1, 0, 0, 0); \
    oacc1 = __builtin_amdgcn_mfma_f32_32x32x16_f16(vfr[3], pa1, oacc1, 0, 0, 0); \
    __builtin_amdgcn_s_setprio(0);                                              \
  } while (0)

  // kv loop: K (consumed first) issued first, then V; compute follows
  for (; it < itend; ++it) {
    const int kt = it << 5;
    LOADK(kt);
    LOADV(kt);
    __builtin_amdgcn_sched_barrier(0);
    BODY(kt);
  }
#undef LOADK
#undef LOADV
#undef BODY

  // per-wave l reduction (in-lane tree + cross-half shfl)
  float l4[4];
#pragma unroll
  for (int r = 0; r < 4; ++r) l4[r] = lacc[r] + lacc[r + 4];
  float ls = (l4[0] + l4[1]) + (l4[2] + l4[3]);
  ls += __shfl_xor(ls, 32);

  // merge: hi-role waves publish partials, lo-role waves combine + store
  if (role == 1) {
    if (hi == 0) { msh[s_strip][q31] = m; lsh[s_strip][q31] = ls; }
#pragma unroll
    for (int g2 = 0; g2 < 4; ++g2)
#pragma unroll
      for (int r = 0; r < 4; ++r) {
        int d0 = (g2 << 3) + (hi << 2) + r;
        Osh[s_strip][q31][d0] = oacc0[(g2 << 2) + r];
        Osh[s_strip][q31][32 + d0] = oacc1[(g2 << 2) + r];
      }
  }
  __syncthreads();
  if (role == 0) {
    float m1 = msh[s_strip][q31], l1 = lsh[s_strip][q31];
    float M = fmaxf(m, m1);
    float c0 = exp2f(m - M);
    float c1 = exp2f(m1 - M);      // empty hi-half: m1=-inf -> c1=0
    float lt = c0 * ls + c1 * l1;
    float il = 1.f / lt;
    size_t obase = ((size_t)b * NT + qg) * NC + h * ND;
#pragma unroll
    for (int g2 = 0; g2 < 4; ++g2) {
      int d0 = (g2 << 3) + (hi << 2);
      half4 h4, h5;
#pragma unroll
      for (int r = 0; r < 4; ++r) {
        h4[r] = (_Float16)((c0 * oacc0[(g2 << 2) + r] + c1 * Osh[s_strip][q31][d0 + r]) * il);
        h5[r] = (_Float16)((c0 * oacc1[(g2 << 2) + r] + c1 * Osh[s_strip][q31][32 + d0 + r]) * il);
      }
      *(half4*)&Oh[obase + d0] = h4;
      *(half4*)&Oh[obase + 32 + d0] = h5;
    }
  }
}

// ---------------- output projection GEMM (fp32 out + bias) ----------------
__global__ __launch_bounds__(256, 2) void k_out(const _Float16* __restrict__ Oh,
                                                const _Float16* __restrict__ WoT,
                                                const float* __restrict__ bo,
                                                float* __restrict__ out) {
  __shared__ __align__(16) _Float16 As[128 * 64];
  __shared__ __align__(16) _Float16 Bs[128 * 64];
  f32x4 acc[4][4];
#pragma unroll
  for (int i = 0; i < 4; ++i)
#pragma unroll
    for (int j = 0; j < 4; ++j) acc[i][j] = (f32x4){0.f, 0.f, 0.f, 0.f};

  const int m0 = blockIdx.y * 128;
  const int n0 = blockIdx.x * 128;
  gemm_mainloop(Oh, WoT, m0, n0, As, Bs, acc);

  const int tid = threadIdx.x, lane = tid & 63, wid = tid >> 6;
  const int wm = wid >> 1, wn = wid & 1, c16 = lane & 15, rg = lane >> 4;
  float bi[4];
#pragma unroll
  for (int ni = 0; ni < 4; ++ni) bi[ni] = bo[n0 + (wn << 6) + (ni << 4) + c16];
#pragma unroll
  for (int mi = 0; mi < 4; ++mi) {
#pragma unroll
    for (int r = 0; r < 4; ++r) {
      int m = m0 + (wm << 6) + (mi << 4) + (rg << 2) + r;
#pragma unroll
      for (int ni = 0; ni < 4; ++ni) {
        int n = n0 + (wn << 6) + (ni << 4) + c16;
        out[(size_t)m * NC + n] = acc[mi][ni][r] + bi[ni];
      }
    }
  }
}

extern "C" void kernel_launch(void* const* d_in, const int* in_sizes, int n_in,
                              void* d_out, int out_size, void* d_ws, size_t ws_size,
                              hipStream_t stream) {
  const float* x  = (const float*)d_in[0];
  const float* Wq = (const float*)d_in[1];
  const float* bq = (const float*)d_in[2];
  const float* Wk = (const float*)d_in[3];
  const float* bk = (const float*)d_in[4];
  const float* Wv = (const float*)d_in[5];
  const float* bv = (const float*)d_in[6];
  const float* Wo = (const float*)d_in[7];
  const float* bo = (const float*)d_in[8];
  float* out = (float*)d_out;

  char* ws = (char*)d_ws;
  _Float16* xh = (_Float16*)ws;                       // 8 MB  [4096][1024]
  _Float16* WT = (_Float16*)(ws + (8ull << 20));      // 8 MB  [4][1024][1024] n-major
  _Float16* Qh = (_Float16*)(ws + (16ull << 20));     // 8 MB  [32][2048][64]
  _Float16* Kh = (_Float16*)(ws + (24ull << 20));     // 8 MB  [32][2048][64]
  _Float16* Vt = (_Float16*)(ws + (32ull << 20));     // 8 MB  [32][64][2048] (transposed)
  _Float16* Oh = (_Float16*)(ws + (40ull << 20));     // 8 MB  [4096][1024]

  k_cvt_x<<<2048, 256, 0, stream>>>(x, xh);
  k_tw<<<dim3(32, 32, 4), dim3(32, 8), 0, stream>>>(Wq, Wk, Wv, Wo, WT);
  k_qkv<<<dim3(24, 32), 256, 0, stream>>>(xh, WT, bq, bk, bv, Qh, Kh, Vt);
  k_attn<<<1024, 256, 0, stream>>>(Qh, Kh, Vt, Oh);
  k_out<<<dim3(8, 32), 256, 0, stream>>>(Oh, WT + (3ull << 20), bo, out);
}

// Round 19
// 129.211 us; speedup vs baseline: 1.8424x; 1.0014x over previous
//
#include <hip/hip_runtime.h>
#include <cstdint>
#include <cstddef>
#include <math.h>

typedef _Float16 half8 __attribute__((ext_vector_type(8)));
typedef _Float16 half4 __attribute__((ext_vector_type(4)));
typedef float f32x4 __attribute__((ext_vector_type(4)));
typedef float f32x16 __attribute__((ext_vector_type(16)));
typedef unsigned int uint2v __attribute__((ext_vector_type(2)));

#define NB  2
#define NT  2048
#define NC  1024
#define NH  16
#define ND  64

__device__ __forceinline__ void gload_lds16(const _Float16* g, _Float16* l) {
  __builtin_amdgcn_global_load_lds((const __attribute__((address_space(1))) void*)g,
                                   (__attribute__((address_space(3))) void*)l, 16, 0, 0);
}

// v_permlane32_swap_b32: r[0]={a.lo,b.lo}, r[1]={a.hi,b.hi}.
// NEVER call with a==b (same SSA value) — regalloc coalescing makes it a self-swap.
__device__ __forceinline__ uint2v plswap(unsigned a, unsigned b) {
  return __builtin_amdgcn_permlane32_swap(a, b, false, false);
}

// ---------------- convert x -> fp16 ----------------
__global__ void k_cvt_x(const float* __restrict__ x, _Float16* __restrict__ xh) {
  const int n4 = (4096 * 1024) / 4;
  int i = blockIdx.x * 256 + threadIdx.x;
  for (; i < n4; i += 2048 * 256) {
    float4 v = ((const float4*)x)[i];
    half4 h = { (_Float16)v.x, (_Float16)v.y, (_Float16)v.z, (_Float16)v.w };
    ((half4*)xh)[i] = h;
  }
}

// ------------- transpose+convert W (1024x1024) -> WT[n][k] fp16 -------------
__global__ void k_tw(const float* __restrict__ W0, const float* __restrict__ W1,
                     const float* __restrict__ W2, const float* __restrict__ W3,
                     _Float16* __restrict__ WT) {
  const float* W = (blockIdx.z == 0) ? W0 : (blockIdx.z == 1) ? W1 : (blockIdx.z == 2) ? W2 : W3;
  _Float16* out = WT + ((size_t)blockIdx.z << 20);
  __shared__ float t[32][33];
  const int x0 = blockIdx.x * 32;  // n
  const int y0 = blockIdx.y * 32;  // k
  const int tx = threadIdx.x, ty = threadIdx.y;  // (32,8)
#pragma unroll
  for (int r = 0; r < 4; ++r)
    t[ty + 8 * r][tx] = W[(size_t)(y0 + ty + 8 * r) * 1024 + x0 + tx];
  __syncthreads();
#pragma unroll
  for (int r = 0; r < 4; ++r)
    out[(size_t)(x0 + ty + 8 * r) * 1024 + y0 + tx] = (_Float16)t[tx][ty + 8 * r];
}

// ---------------- shared GEMM mainloop: C(128x128) = A(128xK) * B^T(128xK) ----------------
__device__ __forceinline__ void gemm_mainloop(const _Float16* __restrict__ A,
                                              const _Float16* __restrict__ Bmat,
                                              int m0, int n0,
                                              _Float16* As, _Float16* Bs,
                                              f32x4 acc[4][4]) {
  const int tid = threadIdx.x;
  const int lane = tid & 63;
  const int wid = tid >> 6;
  const int wm = wid >> 1, wn = wid & 1;
  const int c16 = lane & 15, rg = lane >> 4;

  for (int k0 = 0; k0 < 1024; k0 += 64) {
    __syncthreads();
#pragma unroll
    for (int i = 0; i < 4; ++i) {
      int e = (i * 256 + tid) * 8;       // element index within 128x64 tile
      int row = e >> 6;                  // 0..127
      int chunk = (e & 63) >> 3;         // 0..7 (16B chunk)
      int scol = ((chunk ^ (row & 7)) << 3);  // source-side swizzle (involution)
      gload_lds16(A + (size_t)(m0 + row) * 1024 + k0 + scol,
                  As + (size_t)(i * 256 + (wid << 6)) * 8);
      gload_lds16(Bmat + (size_t)(n0 + row) * 1024 + k0 + scol,
                  Bs + (size_t)(i * 256 + (wid << 6)) * 8);
    }
    __syncthreads();
#pragma unroll
    for (int kk = 0; kk < 2; ++kk) {
      half8 af[4], bfr[4];
#pragma unroll
      for (int mi = 0; mi < 4; ++mi) {
        int row = (wm << 6) + (mi << 4) + c16;
        int chunk = (kk << 2) + rg;
        af[mi] = *(const half8*)&As[(row << 6) + ((chunk ^ (row & 7)) << 3)];
      }
#pragma unroll
      for (int ni = 0; ni < 4; ++ni) {
        int row = (wn << 6) + (ni << 4) + c16;
        int chunk = (kk << 2) + rg;
        bfr[ni] = *(const half8*)&Bs[(row << 6) + ((chunk ^ (row & 7)) << 3)];
      }
#pragma unroll
      for (int mi = 0; mi < 4; ++mi)
#pragma unroll
        for (int ni = 0; ni < 4; ++ni)
          acc[mi][ni] = __builtin_amdgcn_mfma_f32_16x16x32_f16(af[mi], bfr[ni], acc[mi][ni], 0, 0, 0);
    }
  }
}

// ---------------- QKV GEMM + bias + RoPE + scatter ----------------
// Q -> [bh][t][d] scaled by (1/8)*log2(e) (exp2-domain softmax); K -> [bh][t][d];
// V -> transposed [bh][d][t]
__global__ __launch_bounds__(256, 2) void k_qkv(const _Float16* __restrict__ xh,
                                                const _Float16* __restrict__ WT,
                                                const float* __restrict__ bq,
                                                const float* __restrict__ bk,
                                                const float* __restrict__ bv,
                                                _Float16* __restrict__ Qh,
                                                _Float16* __restrict__ Kh,
                                                _Float16* __restrict__ VT) {
  __shared__ __align__(16) _Float16 As[128 * 64];
  __shared__ __align__(16) _Float16 Bs[128 * 64];
  f32x4 acc[4][4];
#pragma unroll
  for (int i = 0; i < 4; ++i)
#pragma unroll
    for (int j = 0; j < 4; ++j) acc[i][j] = (f32x4){0.f, 0.f, 0.f, 0.f};

  const int m0 = blockIdx.y * 128;
  const int ng = blockIdx.x * 128;   // 0..3071
  const int p = ng >> 10;            // 0=q,1=k,2=v
  const int n0 = ng & 1023;
  gemm_mainloop(xh, WT + ((size_t)p << 20), m0, n0, As, Bs, acc);

  const int tid = threadIdx.x, lane = tid & 63, wid = tid >> 6;
  const int wm = wid >> 1, wn = wid & 1, c16 = lane & 15, rg = lane >> 4;
  const float* bias = (p == 0) ? bq : (p == 1) ? bk : bv;
  const int nw = n0 + (wn << 6);
  const int head = nw >> 6;          // wave's 64-col strip is exactly one head
  float bi[4];
#pragma unroll
  for (int ni = 0; ni < 4; ++ni) bi[ni] = bias[nw + (ni << 4) + c16];

  if (p == 2) {  // V: store transposed [bh][d][t], vectorized half4 over t
#pragma unroll
    for (int mi = 0; mi < 4; ++mi) {
      int m = m0 + (wm << 6) + (mi << 4) + (rg << 2);
      int b = m >> 11, t0 = m & 2047;
#pragma unroll
      for (int ni = 0; ni < 4; ++ni) {
        half4 hv;
#pragma unroll
        for (int r = 0; r < 4; ++r) hv[r] = (_Float16)(acc[mi][ni][r] + bi[ni]);
        size_t base = ((size_t)(b * NH + head) * ND + (ni << 4) + c16) * NT + t0;
        *(half4*)&VT[base] = hv;
      }
    }
    return;
  }

  _Float16* Out = (p == 0) ? Qh : Kh;
  // inv_freq[c16] = 10000^(-c16/16) = 2^(-c16 * log2(10000)/16)  (accurate exp2)
  const float invf = exp2f((float)c16 * -0.8304820237218405f);
  // Q scale: (1/sqrt(64)) * log2(e)  -> S from MFMA is directly in exp2 domain
  const float qscale = (p == 0) ? 0.18033688011112042f : 1.0f;

#pragma unroll
  for (int mi = 0; mi < 4; ++mi) {
#pragma unroll
    for (int r = 0; r < 4; ++r) {
      int m = m0 + (wm << 6) + (mi << 4) + (rg << 2) + r;
      int b = m >> 11, t = m & 2047;
      float v0 = acc[mi][0][r] + bi[0];
      float v1 = acc[mi][1][r] + bi[1];
      float v2 = acc[mi][2][r] + bi[2];
      float v3 = acc[mi][3][r] + bi[3];
      {  // RoPE on d<32: pair (d, d+16)
        float th = (float)t * invf;
        float sn, cs;
        sincosf(th, &sn, &cs);   // theta reaches 2047 rad: needs libm range reduction
        float nx = v0 * cs - v1 * sn;
        v1 = v1 * cs + v0 * sn;
        v0 = nx;
      }
      size_t base = ((size_t)(b * NH + head) * NT + t) * ND;
      Out[base + 0 + c16]  = (_Float16)(v0 * qscale);
      Out[base + 16 + c16] = (_Float16)(v1 * qscale);
      Out[base + 32 + c16] = (_Float16)(v2 * qscale);
      Out[base + 48 + c16] = (_Float16)(v3 * qscale);
    }
  }
}

// ------ flash attention: 64-row tiles, 4 waves = 2 strips x (kv-lo, kv-hi) ------
// R18 config + critical-path micro-opts: (1) defer-max checks per-half local max
// first (cross-half bpermute only inside the rare rescale branch); (2) no
// sched_barrier (loads already sit at use sites, VGPR=64); (3) K/V pointers
// strength-reduced (constant byte-stride increments per iteration).
__global__ __launch_bounds__(256, 4) void k_attn(const _Float16* __restrict__ Qh,
                                                 const _Float16* __restrict__ Kh,
                                                 const _Float16* __restrict__ VT,
                                                 _Float16* __restrict__ Oh) {
  const int lin = blockIdx.x;            // 0..1023
  const int xcd = lin & 7;
  const int slot = lin >> 3;             // 0..127 within XCD
  const int rnd = slot >> 5;             // co-residency round 0..3
  const int pos = slot & 31;
  const int bh = (xcd << 2) | (pos & 3); // 4 bh per XCD -> K+V 2MB in per-XCD L2
  const int k8 = pos >> 2;               // 0..7
  const int t = (rnd == 0) ? (31 - k8) : (rnd == 1) ? k8
              : (rnd == 2) ? (23 - k8) : (8 + k8);   // sums to 62 across rounds

  const int tid = threadIdx.x, lane = tid & 63, wid = tid >> 6;  // wid 0..3
  const int s_strip = wid & 1, role = wid >> 1;
  const int q31 = lane & 31, hi = lane >> 5;
  const size_t hb = (size_t)bh * NT * ND;
  const _Float16* Qp = Qh + hb;
  const int b = bh >> 4, h = bh & 15;

  __shared__ float Osh[2][32][65];       // hi-role partial O per strip, +1 pad
  __shared__ float msh[2][32], lsh[2][32];

  const int q0w = (t << 6) + (s_strip << 5);  // this wave's 32 q-rows
  const int qg = q0w + q31;
  const int n = 2 * t + s_strip + 1;     // kv iterations (32 kv each) for this strip
  const int nh2 = (n + 1) >> 1;
  int it = role ? nh2 : 0;
  const int itend = role ? n : nh2;

  half8 qf[4];
#pragma unroll
  for (int c = 0; c < 4; ++c)
    qf[c] = *(const half8*)&Qp[(size_t)qg * ND + (c << 4) + (hi << 3)];

  f32x16 oacc0, oacc1;
#pragma unroll
  for (int r = 0; r < 16; ++r) { oacc0[r] = 0.f; oacc1[r] = 0.f; }
  float lacc[8];
#pragma unroll
  for (int r = 0; r < 8; ++r) lacc[r] = 0.f;
  float m = -INFINITY;

  half8 kA[4], vfr[4];

  // strength-reduced walking pointers (advance by constant strides per iter)
  const _Float16* kp = Kh + hb + (size_t)(((it << 5) + q31) * ND) + (hi << 3);
  const _Float16* vp = VT + hb + (size_t)q31 * NT + (it << 5) + (hi << 3);

#define LOADK() do {                                                            \
    kA[0] = *(const half8*)(kp);                                                \
    kA[1] = *(const half8*)(kp + 16);                                           \
    kA[2] = *(const half8*)(kp + 32);                                           \
    kA[3] = *(const half8*)(kp + 48);                                           \
  } while (0)

#define LOADV() do {                                                            \
    _Pragma("unroll")                                                           \
    for (int dh = 0; dh < 2; ++dh)                                              \
      _Pragma("unroll")                                                         \
      for (int ks = 0; ks < 2; ++ks)                                            \
        vfr[dh * 2 + ks] = *(const half8*)(vp + (size_t)(dh << 5) * NT + (ks << 4)); \
  } while (0)

#define BODY(ktc) do {                                                          \
    f32x16 s;                                                                   \
    _Pragma("unroll")                                                           \
    for (int r = 0; r < 16; ++r) s[r] = 0.f;                                    \
    __builtin_amdgcn_s_setprio(1);                                              \
    _Pragma("unroll")                                                           \
    for (int c = 0; c < 4; ++c)                                                 \
      s = __builtin_amdgcn_mfma_f32_32x32x16_f16(kA[c], qf[c], s, 0, 0, 0);     \
    __builtin_amdgcn_s_setprio(0);                                              \
    if ((ktc) + 31 > q0w) {  /* causal mask: only the strip's final iter */     \
      int rel = qg - (ktc) - (hi << 2);                                         \
      _Pragma("unroll")                                                         \
      for (int r = 0; r < 16; ++r) {                                            \
        int crow = (r & 3) + ((r >> 2) << 3);                                   \
        if (crow > rel) s[r] = -INFINITY;                                       \
      }                                                                         \
    }                                                                           \
    /* per-half local max tree; cross-half swap only when rescale triggers */   \
    float t8[8];                                                                \
    _Pragma("unroll")                                                           \
    for (int r = 0; r < 8; ++r) t8[r] = fmaxf(s[r], s[r + 8]);                  \
    _Pragma("unroll")                                                           \
    for (int r = 0; r < 4; ++r) t8[r] = fmaxf(t8[r], t8[r + 4]);                \
    float pml = fmaxf(fmaxf(t8[0], t8[1]), fmaxf(t8[2], t8[3]));                \
    if (!__all(pml <= m + 11.54f)) {  /* defer-max, THR=8*log2e */              \
      float pm = fmaxf(pml, __shfl_xor(pml, 32));                               \
      float mn = fmaxf(m, pm);                                                  \
      float corr = exp2f(m - mn);                                               \
      m = mn;                                                                   \
      _Pragma("unroll")                                                         \
      for (int r = 0; r < 16; ++r) { oacc0[r] *= corr; oacc1[r] *= corr; }      \
      _Pragma("unroll")                                                         \
      for (int r = 0; r < 8; ++r) lacc[r] *= corr;                              \
    }                                                                           \
    _Pragma("unroll")                                                           \
    for (int r = 0; r < 16; ++r) s[r] = exp2f(s[r] - m);                        \
    _Pragma("unroll")                                                           \
    for (int r = 0; r < 8; ++r) lacc[r] += s[r] + s[r + 8];                     \
    /* pack P; plswap(loWord, hiWord): r[0]->frag lo word, r[1]->hi */          \
    unsigned pw0 = __builtin_bit_cast(unsigned, __builtin_amdgcn_cvt_pkrtz(s[0], s[1]));   \
    unsigned pw1 = __builtin_bit_cast(unsigned, __builtin_amdgcn_cvt_pkrtz(s[2], s[3]));   \
    unsigned pw2 = __builtin_bit_cast(unsigned, __builtin_amdgcn_cvt_pkrtz(s[4], s[5]));   \
    unsigned pw3 = __builtin_bit_cast(unsigned, __builtin_amdgcn_cvt_pkrtz(s[6], s[7]));   \
    unsigned pw4 = __builtin_bit_cast(unsigned, __builtin_amdgcn_cvt_pkrtz(s[8], s[9]));   \
    unsigned pw5 = __builtin_bit_cast(unsigned, __builtin_amdgcn_cvt_pkrtz(s[10], s[11])); \
    unsigned pw6 = __builtin_bit_cast(unsigned, __builtin_amdgcn_cvt_pkrtz(s[12], s[13])); \
    unsigned pw7 = __builtin_bit_cast(unsigned, __builtin_amdgcn_cvt_pkrtz(s[14], s[15])); \
    uint2v rA0 = plswap(pw0, pw2);                                              \
    uint2v rA1 = plswap(pw1, pw3);                                              \
    uint2v rB0 = plswap(pw4, pw6);                                              \
    uint2v rB1 = plswap(pw5, pw7);                                              \
    uint4 ua, ub;                                                               \
    ua.x = rA0[0]; ua.y = rA1[0]; ua.z = rA0[1]; ua.w = rA1[1];                 \
    ub.x = rB0[0]; ub.y = rB1[0]; ub.z = rB0[1]; ub.w = rB1[1];                 \
    half8 pa0 = __builtin_bit_cast(half8, ua);                                  \
    half8 pa1 = __builtin_bit_cast(half8, ub);                                  \
    __builtin_amdgcn_s_setprio(1);                                              \
    oacc0 = __builtin_amdgcn_mfma_f32_32x32x16_f16(vfr[0], pa0, oacc0, 0, 0, 0); \
    oacc0 = __builtin_amdgcn_mfma_f32_32x32x16_f16(vfr[1], pa1, oacc0, 0, 0, 0); \
    oacc1 = __builtin_amdgcn_mfma_f32_32x32x16_f16(vfr[2], pa0, oacc1, 0, 0, 0); \
    oacc1 = __builtin_amdgcn_mfma_f32_32x32x16_f16(vfr[3], pa1, oacc1, 0, 0, 0); \
    __builtin_amdgcn_s_setprio(0);                                              \
  } while (0)

  // kv loop: K (consumed first) issued first, then V; walking pointers
  for (; it < itend; ++it) {
    LOADK();
    LOADV();
    BODY(it << 5);
    kp += 32 * ND;   // next 32 kv rows
    vp += 32;        // next 32 kv cols (t-major)
  }
#undef LOADK
#undef LOADV
#undef BODY

  // per-wave l reduction (in-lane tree + cross-half shfl)
  float l4[4];
#pragma unroll
  for (int r = 0; r < 4; ++r) l4[r] = lacc[r] + lacc[r + 4];
  float ls = (l4[0] + l4[1]) + (l4[2] + l4[3]);
  ls += __shfl_xor(ls, 32);

  // merge: hi-role waves publish partials, lo-role waves combine + store
  if (role == 1) {
    if (hi == 0) { msh[s_strip][q31] = m; lsh[s_strip][q31] = ls; }
#pragma unroll
    for (int g2 = 0; g2 < 4; ++g2)
#pragma unroll
      for (int r = 0; r < 4; ++r) {
        int d0 = (g2 << 3) + (hi << 2) + r;
        Osh[s_strip][q31][d0] = oacc0[(g2 << 2) + r];
        Osh[s_strip][q31][32 + d0] = oacc1[(g2 << 2) + r];
      }
  }
  __syncthreads();
  if (role == 0) {
    float m1 = msh[s_strip][q31], l1 = lsh[s_strip][q31];
    float M = fmaxf(m, m1);
    float c0 = exp2f(m - M);
    float c1 = exp2f(m1 - M);      // empty hi-half: m1=-inf -> c1=0
    float lt = c0 * ls + c1 * l1;
    float il = 1.f / lt;
    size_t obase = ((size_t)b * NT + qg) * NC + h * ND;
#pragma unroll
    for (int g2 = 0; g2 < 4; ++g2) {
      int d0 = (g2 << 3) + (hi << 2);
      half4 h4, h5;
#pragma unroll
      for (int r = 0; r < 4; ++r) {
        h4[r] = (_Float16)((c0 * oacc0[(g2 << 2) + r] + c1 * Osh[s_strip][q31][d0 + r]) * il);
        h5[r] = (_Float16)((c0 * oacc1[(g2 << 2) + r] + c1 * Osh[s_strip][q31][32 + d0 + r]) * il);
      }
      *(half4*)&Oh[obase + d0] = h4;
      *(half4*)&Oh[obase + 32 + d0] = h5;
    }
  }
}

// ---------------- output projection GEMM (fp32 out + bias) ----------------
__global__ __launch_bounds__(256, 2) void k_out(const _Float16* __restrict__ Oh,
                                                const _Float16* __restrict__ WoT,
                                                const float* __restrict__ bo,
                                                float* __restrict__ out) {
  __shared__ __align__(16) _Float16 As[128 * 64];
  __shared__ __align__(16) _Float16 Bs[128 * 64];
  f32x4 acc[4][4];
#pragma unroll
  for (int i = 0; i < 4; ++i)
#pragma unroll
    for (int j = 0; j < 4; ++j) acc[i][j] = (f32x4){0.f, 0.f, 0.f, 0.f};

  const int m0 = blockIdx.y * 128;
  const int n0 = blockIdx.x * 128;
  gemm_mainloop(Oh, WoT, m0, n0, As, Bs, acc);

  const int tid = threadIdx.x, lane = tid & 63, wid = tid >> 6;
  const int wm = wid >> 1, wn = wid & 1, c16 = lane & 15, rg = lane >> 4;
  float bi[4];
#pragma unroll
  for (int ni = 0; ni < 4; ++ni) bi[ni] = bo[n0 + (wn << 6) + (ni << 4) + c16];
#pragma unroll
  for (int mi = 0; mi < 4; ++mi) {
#pragma unroll
    for (int r = 0; r < 4; ++r) {
      int m = m0 + (wm << 6) + (mi << 4) + (rg << 2) + r;
#pragma unroll
      for (int ni = 0; ni < 4; ++ni) {
        int n = n0 + (wn << 6) + (ni << 4) + c16;
        out[(size_t)m * NC + n] = acc[mi][ni][r] + bi[ni];
      }
    }
  }
}

extern "C" void kernel_launch(void* const* d_in, const int* in_sizes, int n_in,
                              void* d_out, int out_size, void* d_ws, size_t ws_size,
                              hipStream_t stream) {
  const float* x  = (const float*)d_in[0];
  const float* Wq = (const float*)d_in[1];
  const float* bq = (const float*)d_in[2];
  const float* Wk = (const float*)d_in[3];
  const float* bk = (const float*)d_in[4];
  const float* Wv = (const float*)d_in[5];
  const float* bv = (const float*)d_in[6];
  const float* Wo = (const float*)d_in[7];
  const float* bo = (const float*)d_in[8];
  float* out = (float*)d_out;

  char* ws = (char*)d_ws;
  _Float16* xh = (_Float16*)ws;                       // 8 MB  [4096][1024]
  _Float16* WT = (_Float16*)(ws + (8ull << 20));      // 8 MB  [4][1024][1024] n-major
  _Float16* Qh = (_Float16*)(ws + (16ull << 20));     // 8 MB  [32][2048][64]
  _Float16* Kh = (_Float16*)(ws + (24ull << 20));     // 8 MB  [32][2048][64]
  _Float16* Vt = (_Float16*)(ws + (32ull << 20));     // 8 MB  [32][64][2048] (transposed)
  _Float16* Oh = (_Float16*)(ws + (40ull << 20));     // 8 MB  [4096][1024]

  k_cvt_x<<<2048, 256, 0, stream>>>(x, xh);
  k_tw<<<dim3(32, 32, 4), dim3(32, 8), 0, stream>>>(Wq, Wk, Wv, Wo, WT);
  k_qkv<<<dim3(24, 32), 256, 0, stream>>>(xh, WT, bq, bk, bv, Qh, Kh, Vt);
  k_attn<<<1024, 256, 0, stream>>>(Qh, Kh, Vt, Oh);
  k_out<<<dim3(8, 32), 256, 0, stream>>>(Oh, WT + (3ull << 20), bo, out);
}

// Round 20
// 127.363 us; speedup vs baseline: 1.8692x; 1.0145x over previous
//
#include <hip/hip_runtime.h>
#include <cstdint>
#include <cstddef>
#include <math.h>

typedef _Float16 half8 __attribute__((ext_vector_type(8)));
typedef _Float16 half4 __attribute__((ext_vector_type(4)));
typedef float f32x4 __attribute__((ext_vector_type(4)));
typedef float f32x16 __attribute__((ext_vector_type(16)));
typedef unsigned int uint2v __attribute__((ext_vector_type(2)));

#define NB  2
#define NT  2048
#define NC  1024
#define NH  16
#define ND  64

__device__ __forceinline__ void gload_lds16(const _Float16* g, _Float16* l) {
  __builtin_amdgcn_global_load_lds((const __attribute__((address_space(1))) void*)g,
                                   (__attribute__((address_space(3))) void*)l, 16, 0, 0);
}

// v_permlane32_swap_b32: r[0]={a.lo,b.lo}, r[1]={a.hi,b.hi}.
// NEVER call with a==b (same SSA value) — regalloc coalescing makes it a self-swap.
__device__ __forceinline__ uint2v plswap(unsigned a, unsigned b) {
  return __builtin_amdgcn_permlane32_swap(a, b, false, false);
}

// ------------- fused prep: W transposes (z<4) + x fp32->fp16 convert (z==4) -------------
// one launch instead of two; the two BW-bound streams overlap on the fabric.
__global__ void k_prep(const float* __restrict__ x, const float* __restrict__ W0,
                       const float* __restrict__ W1, const float* __restrict__ W2,
                       const float* __restrict__ W3,
                       _Float16* __restrict__ xh, _Float16* __restrict__ WT) {
  const int tx = threadIdx.x, ty = threadIdx.y;  // (32,8)
  if (blockIdx.z == 4) {  // convert x: 1024 blocks x 256 thr x 4 float4
    const int tid = ty * 32 + tx;
    const int base = (blockIdx.y * 32 + blockIdx.x) * 1024 + tid;
#pragma unroll
    for (int r = 0; r < 4; ++r) {
      float4 v = ((const float4*)x)[base + r * 256];
      half4 hv = { (_Float16)v.x, (_Float16)v.y, (_Float16)v.z, (_Float16)v.w };
      ((half4*)xh)[base + r * 256] = hv;
    }
    return;
  }
  const float* W = (blockIdx.z == 0) ? W0 : (blockIdx.z == 1) ? W1 : (blockIdx.z == 2) ? W2 : W3;
  _Float16* out = WT + ((size_t)blockIdx.z << 20);
  __shared__ float t[32][33];
  const int x0 = blockIdx.x * 32;  // n
  const int y0 = blockIdx.y * 32;  // k
#pragma unroll
  for (int r = 0; r < 4; ++r)
    t[ty + 8 * r][tx] = W[(size_t)(y0 + ty + 8 * r) * 1024 + x0 + tx];
  __syncthreads();
#pragma unroll
  for (int r = 0; r < 4; ++r)
    out[(size_t)(x0 + ty + 8 * r) * 1024 + y0 + tx] = (_Float16)t[tx][ty + 8 * r];
}

// ---------------- shared GEMM mainloop: C(128x128) = A(128xK) * B^T(128xK) ----------------
__device__ __forceinline__ void gemm_mainloop(const _Float16* __restrict__ A,
                                              const _Float16* __restrict__ Bmat,
                                              int m0, int n0,
                                              _Float16* As, _Float16* Bs,
                                              f32x4 acc[4][4]) {
  const int tid = threadIdx.x;
  const int lane = tid & 63;
  const int wid = tid >> 6;
  const int wm = wid >> 1, wn = wid & 1;
  const int c16 = lane & 15, rg = lane >> 4;

  for (int k0 = 0; k0 < 1024; k0 += 64) {
    __syncthreads();
#pragma unroll
    for (int i = 0; i < 4; ++i) {
      int e = (i * 256 + tid) * 8;       // element index within 128x64 tile
      int row = e >> 6;                  // 0..127
      int chunk = (e & 63) >> 3;         // 0..7 (16B chunk)
      int scol = ((chunk ^ (row & 7)) << 3);  // source-side swizzle (involution)
      gload_lds16(A + (size_t)(m0 + row) * 1024 + k0 + scol,
                  As + (size_t)(i * 256 + (wid << 6)) * 8);
      gload_lds16(Bmat + (size_t)(n0 + row) * 1024 + k0 + scol,
                  Bs + (size_t)(i * 256 + (wid << 6)) * 8);
    }
    __syncthreads();
#pragma unroll
    for (int kk = 0; kk < 2; ++kk) {
      half8 af[4], bfr[4];
#pragma unroll
      for (int mi = 0; mi < 4; ++mi) {
        int row = (wm << 6) + (mi << 4) + c16;
        int chunk = (kk << 2) + rg;
        af[mi] = *(const half8*)&As[(row << 6) + ((chunk ^ (row & 7)) << 3)];
      }
#pragma unroll
      for (int ni = 0; ni < 4; ++ni) {
        int row = (wn << 6) + (ni << 4) + c16;
        int chunk = (kk << 2) + rg;
        bfr[ni] = *(const half8*)&Bs[(row << 6) + ((chunk ^ (row & 7)) << 3)];
      }
#pragma unroll
      for (int mi = 0; mi < 4; ++mi)
#pragma unroll
        for (int ni = 0; ni < 4; ++ni)
          acc[mi][ni] = __builtin_amdgcn_mfma_f32_16x16x32_f16(af[mi], bfr[ni], acc[mi][ni], 0, 0, 0);
    }
  }
}

// ---------------- QKV GEMM + bias + RoPE + scatter ----------------
// Q -> [bh][t][d] scaled by (1/8)*log2(e) (exp2-domain softmax); K -> [bh][t][d];
// V -> transposed [bh][d][t]
__global__ __launch_bounds__(256, 2) void k_qkv(const _Float16* __restrict__ xh,
                                                const _Float16* __restrict__ WT,
                                                const float* __restrict__ bq,
                                                const float* __restrict__ bk,
                                                const float* __restrict__ bv,
                                                _Float16* __restrict__ Qh,
                                                _Float16* __restrict__ Kh,
                                                _Float16* __restrict__ VT) {
  __shared__ __align__(16) _Float16 As[128 * 64];
  __shared__ __align__(16) _Float16 Bs[128 * 64];
  f32x4 acc[4][4];
#pragma unroll
  for (int i = 0; i < 4; ++i)
#pragma unroll
    for (int j = 0; j < 4; ++j) acc[i][j] = (f32x4){0.f, 0.f, 0.f, 0.f};

  const int m0 = blockIdx.y * 128;
  const int ng = blockIdx.x * 128;   // 0..3071
  const int p = ng >> 10;            // 0=q,1=k,2=v
  const int n0 = ng & 1023;
  gemm_mainloop(xh, WT + ((size_t)p << 20), m0, n0, As, Bs, acc);

  const int tid = threadIdx.x, lane = tid & 63, wid = tid >> 6;
  const int wm = wid >> 1, wn = wid & 1, c16 = lane & 15, rg = lane >> 4;
  const float* bias = (p == 0) ? bq : (p == 1) ? bk : bv;
  const int nw = n0 + (wn << 6);
  const int head = nw >> 6;          // wave's 64-col strip is exactly one head
  float bi[4];
#pragma unroll
  for (int ni = 0; ni < 4; ++ni) bi[ni] = bias[nw + (ni << 4) + c16];

  if (p == 2) {  // V: store transposed [bh][d][t], vectorized half4 over t
#pragma unroll
    for (int mi = 0; mi < 4; ++mi) {
      int m = m0 + (wm << 6) + (mi << 4) + (rg << 2);
      int b = m >> 11, t0 = m & 2047;
#pragma unroll
      for (int ni = 0; ni < 4; ++ni) {
        half4 hv;
#pragma unroll
        for (int r = 0; r < 4; ++r) hv[r] = (_Float16)(acc[mi][ni][r] + bi[ni]);
        size_t base = ((size_t)(b * NH + head) * ND + (ni << 4) + c16) * NT + t0;
        *(half4*)&VT[base] = hv;
      }
    }
    return;
  }

  _Float16* Out = (p == 0) ? Qh : Kh;
  // inv_freq[c16] = 10000^(-c16/16) = 2^(-c16 * log2(10000)/16)  (accurate exp2)
  const float invf = exp2f((float)c16 * -0.8304820237218405f);
  // Q scale: (1/sqrt(64)) * log2(e)  -> S from MFMA is directly in exp2 domain
  const float qscale = (p == 0) ? 0.18033688011112042f : 1.0f;

#pragma unroll
  for (int mi = 0; mi < 4; ++mi) {
#pragma unroll
    for (int r = 0; r < 4; ++r) {
      int m = m0 + (wm << 6) + (mi << 4) + (rg << 2) + r;
      int b = m >> 11, t = m & 2047;
      float v0 = acc[mi][0][r] + bi[0];
      float v1 = acc[mi][1][r] + bi[1];
      float v2 = acc[mi][2][r] + bi[2];
      float v3 = acc[mi][3][r] + bi[3];
      {  // RoPE on d<32: pair (d, d+16)
        float th = (float)t * invf;
        float sn, cs;
        sincosf(th, &sn, &cs);   // theta reaches 2047 rad: needs libm range reduction
        float nx = v0 * cs - v1 * sn;
        v1 = v1 * cs + v0 * sn;
        v0 = nx;
      }
      size_t base = ((size_t)(b * NH + head) * NT + t) * ND;
      Out[base + 0 + c16]  = (_Float16)(v0 * qscale);
      Out[base + 16 + c16] = (_Float16)(v1 * qscale);
      Out[base + 32 + c16] = (_Float16)(v2 * qscale);
      Out[base + 48 + c16] = (_Float16)(v3 * qscale);
    }
  }
}

// ------ flash attention: 64-row tiles, 4 waves = 2 strips x (kv-lo, kv-hi) ------
// R19 config (best measured: 72.6us attn, zero spill at the exact 128-reg cap).
__global__ __launch_bounds__(256, 4) void k_attn(const _Float16* __restrict__ Qh,
                                                 const _Float16* __restrict__ Kh,
                                                 const _Float16* __restrict__ VT,
                                                 _Float16* __restrict__ Oh) {
  const int lin = blockIdx.x;            // 0..1023
  const int xcd = lin & 7;
  const int slot = lin >> 3;             // 0..127 within XCD
  const int rnd = slot >> 5;             // co-residency round 0..3
  const int pos = slot & 31;
  const int bh = (xcd << 2) | (pos & 3); // 4 bh per XCD -> K+V 2MB in per-XCD L2
  const int k8 = pos >> 2;               // 0..7
  const int t = (rnd == 0) ? (31 - k8) : (rnd == 1) ? k8
              : (rnd == 2) ? (23 - k8) : (8 + k8);   // sums to 62 across rounds

  const int tid = threadIdx.x, lane = tid & 63, wid = tid >> 6;  // wid 0..3
  const int s_strip = wid & 1, role = wid >> 1;
  const int q31 = lane & 31, hi = lane >> 5;
  const size_t hb = (size_t)bh * NT * ND;
  const _Float16* Qp = Qh + hb;
  const int b = bh >> 4, h = bh & 15;

  __shared__ float Osh[2][32][65];       // hi-role partial O per strip, +1 pad
  __shared__ float msh[2][32], lsh[2][32];

  const int q0w = (t << 6) + (s_strip << 5);  // this wave's 32 q-rows
  const int qg = q0w + q31;
  const int n = 2 * t + s_strip + 1;     // kv iterations (32 kv each) for this strip
  const int nh2 = (n + 1) >> 1;
  int it = role ? nh2 : 0;
  const int itend = role ? n : nh2;

  half8 qf[4];
#pragma unroll
  for (int c = 0; c < 4; ++c)
    qf[c] = *(const half8*)&Qp[(size_t)qg * ND + (c << 4) + (hi << 3)];

  f32x16 oacc0, oacc1;
#pragma unroll
  for (int r = 0; r < 16; ++r) { oacc0[r] = 0.f; oacc1[r] = 0.f; }
  float lacc[8];
#pragma unroll
  for (int r = 0; r < 8; ++r) lacc[r] = 0.f;
  float m = -INFINITY;

  half8 kA[4], vfr[4];

  // strength-reduced walking pointers (advance by constant strides per iter)
  const _Float16* kp = Kh + hb + (size_t)(((it << 5) + q31) * ND) + (hi << 3);
  const _Float16* vp = VT + hb + (size_t)q31 * NT + (it << 5) + (hi << 3);

#define LOADK() do {                                                            \
    kA[0] = *(const half8*)(kp);                                                \
    kA[1] = *(const half8*)(kp + 16);                                           \
    kA[2] = *(const half8*)(kp + 32);                                           \
    kA[3] = *(const half8*)(kp + 48);                                           \
  } while (0)

#define LOADV() do {                                                            \
    _Pragma("unroll")                                                           \
    for (int dh = 0; dh < 2; ++dh)                                              \
      _Pragma("unroll")                                                         \
      for (int ks = 0; ks < 2; ++ks)                                            \
        vfr[dh * 2 + ks] = *(const half8*)(vp + (size_t)(dh << 5) * NT + (ks << 4)); \
  } while (0)

#define BODY(ktc) do {                                                          \
    f32x16 s;                                                                   \
    _Pragma("unroll")                                                           \
    for (int r = 0; r < 16; ++r) s[r] = 0.f;                                    \
    __builtin_amdgcn_s_setprio(1);                                              \
    _Pragma("unroll")                                                           \
    for (int c = 0; c < 4; ++c)                                                 \
      s = __builtin_amdgcn_mfma_f32_32x32x16_f16(kA[c], qf[c], s, 0, 0, 0);     \
    __builtin_amdgcn_s_setprio(0);                                              \
    if ((ktc) + 31 > q0w) {  /* causal mask: only the strip's final iter */     \
      int rel = qg - (ktc) - (hi << 2);                                         \
      _Pragma("unroll")                                                         \
      for (int r = 0; r < 16; ++r) {                                            \
        int crow = (r & 3) + ((r >> 2) << 3);                                   \
        if (crow > rel) s[r] = -INFINITY;                                       \
      }                                                                         \
    }                                                                           \
    /* per-half local max tree; cross-half swap only when rescale triggers */   \
    float t8[8];                                                                \
    _Pragma("unroll")                                                           \
    for (int r = 0; r < 8; ++r) t8[r] = fmaxf(s[r], s[r + 8]);                  \
    _Pragma("unroll")                                                           \
    for (int r = 0; r < 4; ++r) t8[r] = fmaxf(t8[r], t8[r + 4]);                \
    float pml = fmaxf(fmaxf(t8[0], t8[1]), fmaxf(t8[2], t8[3]));                \
    if (!__all(pml <= m + 11.54f)) {  /* defer-max, THR=8*log2e */              \
      float pm = fmaxf(pml, __shfl_xor(pml, 32));                               \
      float mn = fmaxf(m, pm);                                                  \
      float corr = exp2f(m - mn);                                               \
      m = mn;                                                                   \
      _Pragma("unroll")                                                         \
      for (int r = 0; r < 16; ++r) { oacc0[r] *= corr; oacc1[r] *= corr; }      \
      _Pragma("unroll")                                                         \
      for (int r = 0; r < 8; ++r) lacc[r] *= corr;                              \
    }                                                                           \
    _Pragma("unroll")                                                           \
    for (int r = 0; r < 16; ++r) s[r] = exp2f(s[r] - m);                        \
    _Pragma("unroll")                                                           \
    for (int r = 0; r < 8; ++r) lacc[r] += s[r] + s[r + 8];                     \
    /* pack P; plswap(loWord, hiWord): r[0]->frag lo word, r[1]->hi */          \
    unsigned pw0 = __builtin_bit_cast(unsigned, __builtin_amdgcn_cvt_pkrtz(s[0], s[1]));   \
    unsigned pw1 = __builtin_bit_cast(unsigned, __builtin_amdgcn_cvt_pkrtz(s[2], s[3]));   \
    unsigned pw2 = __builtin_bit_cast(unsigned, __builtin_amdgcn_cvt_pkrtz(s[4], s[5]));   \
    unsigned pw3 = __builtin_bit_cast(unsigned, __builtin_amdgcn_cvt_pkrtz(s[6], s[7]));   \
    unsigned pw4 = __builtin_bit_cast(unsigned, __builtin_amdgcn_cvt_pkrtz(s[8], s[9]));   \
    unsigned pw5 = __builtin_bit_cast(unsigned, __builtin_amdgcn_cvt_pkrtz(s[10], s[11])); \
    unsigned pw6 = __builtin_bit_cast(unsigned, __builtin_amdgcn_cvt_pkrtz(s[12], s[13])); \
    unsigned pw7 = __builtin_bit_cast(unsigned, __builtin_amdgcn_cvt_pkrtz(s[14], s[15])); \
    uint2v rA0 = plswap(pw0, pw2);                                              \
    uint2v rA1 = plswap(pw1, pw3);                                              \
    uint2v rB0 = plswap(pw4, pw6);                                              \
    uint2v rB1 = plswap(pw5, pw7);                                              \
    uint4 ua, ub;                                                               \
    ua.x = rA0[0]; ua.y = rA1[0]; ua.z = rA0[1]; ua.w = rA1[1];                 \
    ub.x = rB0[0]; ub.y = rB1[0]; ub.z = rB0[1]; ub.w = rB1[1];                 \
    half8 pa0 = __builtin_bit_cast(half8, ua);                                  \
    half8 pa1 = __builtin_bit_cast(half8, ub);                                  \
    __builtin_amdgcn_s_setprio(1);                                              \
    oacc0 = __builtin_amdgcn_mfma_f32_32x32x16_f16(vfr[0], pa0, oacc0, 0, 0, 0); \
    oacc0 = __builtin_amdgcn_mfma_f32_32x32x16_f16(vfr[1], pa1, oacc0, 0, 0, 0); \
    oacc1 = __builtin_amdgcn_mfma_f32_32x32x16_f16(vfr[2], pa0, oacc1, 0, 0, 0); \
    oacc1 = __builtin_amdgcn_mfma_f32_32x32x16_f16(vfr[3], pa1, oacc1, 0, 0, 0); \
    __builtin_amdgcn_s_setprio(0);                                              \
  } while (0)

  // kv loop: K (consumed first) issued first, then V; walking pointers
  for (; it < itend; ++it) {
    LOADK();
    LOADV();
    BODY(it << 5);
    kp += 32 * ND;   // next 32 kv rows
    vp += 32;        // next 32 kv cols (t-major)
  }
#undef LOADK
#undef LOADV
#undef BODY

  // per-wave l reduction (in-lane tree + cross-half shfl)
  float l4[4];
#pragma unroll
  for (int r = 0; r < 4; ++r) l4[r] = lacc[r] + lacc[r + 4];
  float ls = (l4[0] + l4[1]) + (l4[2] + l4[3]);
  ls += __shfl_xor(ls, 32);

  // merge: hi-role waves publish partials, lo-role waves combine + store
  if (role == 1) {
    if (hi == 0) { msh[s_strip][q31] = m; lsh[s_strip][q31] = ls; }
#pragma unroll
    for (int g2 = 0; g2 < 4; ++g2)
#pragma unroll
      for (int r = 0; r < 4; ++r) {
        int d0 = (g2 << 3) + (hi << 2) + r;
        Osh[s_strip][q31][d0] = oacc0[(g2 << 2) + r];
        Osh[s_strip][q31][32 + d0] = oacc1[(g2 << 2) + r];
      }
  }
  __syncthreads();
  if (role == 0) {
    float m1 = msh[s_strip][q31], l1 = lsh[s_strip][q31];
    float M = fmaxf(m, m1);
    float c0 = exp2f(m - M);
    float c1 = exp2f(m1 - M);      // empty hi-half: m1=-inf -> c1=0
    float lt = c0 * ls + c1 * l1;
    float il = 1.f / lt;
    size_t obase = ((size_t)b * NT + qg) * NC + h * ND;
#pragma unroll
    for (int g2 = 0; g2 < 4; ++g2) {
      int d0 = (g2 << 3) + (hi << 2);
      half4 h4, h5;
#pragma unroll
      for (int r = 0; r < 4; ++r) {
        h4[r] = (_Float16)((c0 * oacc0[(g2 << 2) + r] + c1 * Osh[s_strip][q31][d0 + r]) * il);
        h5[r] = (_Float16)((c0 * oacc1[(g2 << 2) + r] + c1 * Osh[s_strip][q31][32 + d0 + r]) * il);
      }
      *(half4*)&Oh[obase + d0] = h4;
      *(half4*)&Oh[obase + 32 + d0] = h5;
    }
  }
}

// ---------------- output projection GEMM (fp32 out + bias) ----------------
__global__ __launch_bounds__(256, 2) void k_out(const _Float16* __restrict__ Oh,
                                                const _Float16* __restrict__ WoT,
                                                const float* __restrict__ bo,
                                                float* __restrict__ out) {
  __shared__ __align__(16) _Float16 As[128 * 64];
  __shared__ __align__(16) _Float16 Bs[128 * 64];
  f32x4 acc[4][4];
#pragma unroll
  for (int i = 0; i < 4; ++i)
#pragma unroll
    for (int j = 0; j < 4; ++j) acc[i][j] = (f32x4){0.f, 0.f, 0.f, 0.f};

  const int m0 = blockIdx.y * 128;
  const int n0 = blockIdx.x * 128;
  gemm_mainloop(Oh, WoT, m0, n0, As, Bs, acc);

  const int tid = threadIdx.x, lane = tid & 63, wid = tid >> 6;
  const int wm = wid >> 1, wn = wid & 1, c16 = lane & 15, rg = lane >> 4;
  float bi[4];
#pragma unroll
  for (int ni = 0; ni < 4; ++ni) bi[ni] = bo[n0 + (wn << 6) + (ni << 4) + c16];
#pragma unroll
  for (int mi = 0; mi < 4; ++mi) {
#pragma unroll
    for (int r = 0; r < 4; ++r) {
      int m = m0 + (wm << 6) + (mi << 4) + (rg << 2) + r;
#pragma unroll
      for (int ni = 0; ni < 4; ++ni) {
        int n = n0 + (wn << 6) + (ni << 4) + c16;
        out[(size_t)m * NC + n] = acc[mi][ni][r] + bi[ni];
      }
    }
  }
}

extern "C" void kernel_launch(void* const* d_in, const int* in_sizes, int n_in,
                              void* d_out, int out_size, void* d_ws, size_t ws_size,
                              hipStream_t stream) {
  const float* x  = (const float*)d_in[0];
  const float* Wq = (const float*)d_in[1];
  const float* bq = (const float*)d_in[2];
  const float* Wk = (const float*)d_in[3];
  const float* bk = (const float*)d_in[4];
  const float* Wv = (const float*)d_in[5];
  const float* bv = (const float*)d_in[6];
  const float* Wo = (const float*)d_in[7];
  const float* bo = (const float*)d_in[8];
  float* out = (float*)d_out;

  char* ws = (char*)d_ws;
  _Float16* xh = (_Float16*)ws;                       // 8 MB  [4096][1024]
  _Float16* WT = (_Float16*)(ws + (8ull << 20));      // 8 MB  [4][1024][1024] n-major
  _Float16* Qh = (_Float16*)(ws + (16ull << 20));     // 8 MB  [32][2048][64]
  _Float16* Kh = (_Float16*)(ws + (24ull << 20));     // 8 MB  [32][2048][64]
  _Float16* Vt = (_Float16*)(ws + (32ull << 20));     // 8 MB  [32][64][2048] (transposed)
  _Float16* Oh = (_Float16*)(ws + (40ull << 20));     // 8 MB  [4096][1024]

  k_prep<<<dim3(32, 32, 5), dim3(32, 8), 0, stream>>>(x, Wq, Wk, Wv, Wo, xh, WT);
  k_qkv<<<dim3(24, 32), 256, 0, stream>>>(xh, WT, bq, bk, bv, Qh, Kh, Vt);
  k_attn<<<1024, 256, 0, stream>>>(Qh, Kh, Vt, Oh);
  k_out<<<dim3(8, 32), 256, 0, stream>>>(Oh, WT + (3ull << 20), bo, out);
}

// Round 21
// 126.760 us; speedup vs baseline: 1.8781x; 1.0048x over previous
//
#include <hip/hip_runtime.h>
#include <cstdint>
#include <cstddef>
#include <math.h>

typedef _Float16 half8 __attribute__((ext_vector_type(8)));
typedef _Float16 half4 __attribute__((ext_vector_type(4)));
typedef float f32x4 __attribute__((ext_vector_type(4)));
typedef float f32x16 __attribute__((ext_vector_type(16)));
typedef unsigned int uint2v __attribute__((ext_vector_type(2)));

#define NB  2
#define NT  2048
#define NC  1024
#define NH  16
#define ND  64

__device__ __forceinline__ void gload_lds16(const _Float16* g, _Float16* l) {
  __builtin_amdgcn_global_load_lds((const __attribute__((address_space(1))) void*)g,
                                   (__attribute__((address_space(3))) void*)l, 16, 0, 0);
}

// v_permlane32_swap_b32: r[0]={a.lo,b.lo}, r[1]={a.hi,b.hi}.
// NEVER call with a==b (same SSA value) — regalloc coalescing makes it a self-swap.
__device__ __forceinline__ uint2v plswap(unsigned a, unsigned b) {
  return __builtin_amdgcn_permlane32_swap(a, b, false, false);
}

// ------------- fused prep: W transposes (z<4) + x convert (z==4) + RoPE tables (z==5) ----
// RoPE tables: ct/st[t][j] = cos/sin(t * 10000^(-j/16)), t<2048, j<16. Computed once here
// (32768 libm sincosf calls, parallel) instead of 131072 redundant calls in k_qkv epilogues
// (theta reaches 2047 rad -> slow Payne-Hanek path). Tables live in the Oh region, which is
// dead until k_attn overwrites it (k_qkv consumes tables first; single-stream ordering).
__global__ void k_prep(const float* __restrict__ x, const float* __restrict__ W0,
                       const float* __restrict__ W1, const float* __restrict__ W2,
                       const float* __restrict__ W3,
                       _Float16* __restrict__ xh, _Float16* __restrict__ WT,
                       float* __restrict__ ct, float* __restrict__ st) {
  const int tx = threadIdx.x, ty = threadIdx.y;  // (32,8)
  if (blockIdx.z == 5) {  // RoPE tables: first 128 blocks cover 2048*16 entries
    const int blk = blockIdx.y * 32 + blockIdx.x;
    if (blk < 128) {
      int g = blk * 256 + ty * 32 + tx;   // 0..32767
      int t = g >> 4, j = g & 15;
      float invf = exp2f((float)j * -0.8304820237218405f);
      float sn, cs;
      sincosf((float)t * invf, &sn, &cs);
      ct[g] = cs;
      st[g] = sn;
    }
    return;
  }
  if (blockIdx.z == 4) {  // convert x: 1024 blocks x 256 thr x 4 float4
    const int tid = ty * 32 + tx;
    const int base = (blockIdx.y * 32 + blockIdx.x) * 1024 + tid;
#pragma unroll
    for (int r = 0; r < 4; ++r) {
      float4 v = ((const float4*)x)[base + r * 256];
      half4 hv = { (_Float16)v.x, (_Float16)v.y, (_Float16)v.z, (_Float16)v.w };
      ((half4*)xh)[base + r * 256] = hv;
    }
    return;
  }
  const float* W = (blockIdx.z == 0) ? W0 : (blockIdx.z == 1) ? W1 : (blockIdx.z == 2) ? W2 : W3;
  _Float16* out = WT + ((size_t)blockIdx.z << 20);
  __shared__ float t[32][33];
  const int x0 = blockIdx.x * 32;  // n
  const int y0 = blockIdx.y * 32;  // k
#pragma unroll
  for (int r = 0; r < 4; ++r)
    t[ty + 8 * r][tx] = W[(size_t)(y0 + ty + 8 * r) * 1024 + x0 + tx];
  __syncthreads();
#pragma unroll
  for (int r = 0; r < 4; ++r)
    out[(size_t)(x0 + ty + 8 * r) * 1024 + y0 + tx] = (_Float16)t[tx][ty + 8 * r];
}

// ---------------- shared GEMM mainloop: C(128x128) = A(128xK) * B^T(128xK) ----------------
__device__ __forceinline__ void gemm_mainloop(const _Float16* __restrict__ A,
                                              const _Float16* __restrict__ Bmat,
                                              int m0, int n0,
                                              _Float16* As, _Float16* Bs,
                                              f32x4 acc[4][4]) {
  const int tid = threadIdx.x;
  const int lane = tid & 63;
  const int wid = tid >> 6;
  const int wm = wid >> 1, wn = wid & 1;
  const int c16 = lane & 15, rg = lane >> 4;

  for (int k0 = 0; k0 < 1024; k0 += 64) {
    __syncthreads();
#pragma unroll
    for (int i = 0; i < 4; ++i) {
      int e = (i * 256 + tid) * 8;       // element index within 128x64 tile
      int row = e >> 6;                  // 0..127
      int chunk = (e & 63) >> 3;         // 0..7 (16B chunk)
      int scol = ((chunk ^ (row & 7)) << 3);  // source-side swizzle (involution)
      gload_lds16(A + (size_t)(m0 + row) * 1024 + k0 + scol,
                  As + (size_t)(i * 256 + (wid << 6)) * 8);
      gload_lds16(Bmat + (size_t)(n0 + row) * 1024 + k0 + scol,
                  Bs + (size_t)(i * 256 + (wid << 6)) * 8);
    }
    __syncthreads();
#pragma unroll
    for (int kk = 0; kk < 2; ++kk) {
      half8 af[4], bfr[4];
#pragma unroll
      for (int mi = 0; mi < 4; ++mi) {
        int row = (wm << 6) + (mi << 4) + c16;
        int chunk = (kk << 2) + rg;
        af[mi] = *(const half8*)&As[(row << 6) + ((chunk ^ (row & 7)) << 3)];
      }
#pragma unroll
      for (int ni = 0; ni < 4; ++ni) {
        int row = (wn << 6) + (ni << 4) + c16;
        int chunk = (kk << 2) + rg;
        bfr[ni] = *(const half8*)&Bs[(row << 6) + ((chunk ^ (row & 7)) << 3)];
      }
#pragma unroll
      for (int mi = 0; mi < 4; ++mi)
#pragma unroll
        for (int ni = 0; ni < 4; ++ni)
          acc[mi][ni] = __builtin_amdgcn_mfma_f32_16x16x32_f16(af[mi], bfr[ni], acc[mi][ni], 0, 0, 0);
    }
  }
}

// ---------------- QKV GEMM + bias + RoPE (table) + scatter ----------------
// Q -> [bh][t][d] scaled by (1/8)*log2(e) (exp2-domain softmax); K -> [bh][t][d];
// V -> transposed [bh][d][t]
__global__ __launch_bounds__(256, 2) void k_qkv(const _Float16* __restrict__ xh,
                                                const _Float16* __restrict__ WT,
                                                const float* __restrict__ bq,
                                                const float* __restrict__ bk,
                                                const float* __restrict__ bv,
                                                const float* __restrict__ ct,
                                                const float* __restrict__ st,
                                                _Float16* __restrict__ Qh,
                                                _Float16* __restrict__ Kh,
                                                _Float16* __restrict__ VT) {
  __shared__ __align__(16) _Float16 As[128 * 64];
  __shared__ __align__(16) _Float16 Bs[128 * 64];
  f32x4 acc[4][4];
#pragma unroll
  for (int i = 0; i < 4; ++i)
#pragma unroll
    for (int j = 0; j < 4; ++j) acc[i][j] = (f32x4){0.f, 0.f, 0.f, 0.f};

  const int m0 = blockIdx.y * 128;
  const int ng = blockIdx.x * 128;   // 0..3071
  const int p = ng >> 10;            // 0=q,1=k,2=v
  const int n0 = ng & 1023;
  gemm_mainloop(xh, WT + ((size_t)p << 20), m0, n0, As, Bs, acc);

  const int tid = threadIdx.x, lane = tid & 63, wid = tid >> 6;
  const int wm = wid >> 1, wn = wid & 1, c16 = lane & 15, rg = lane >> 4;
  const float* bias = (p == 0) ? bq : (p == 1) ? bk : bv;
  const int nw = n0 + (wn << 6);
  const int head = nw >> 6;          // wave's 64-col strip is exactly one head
  float bi[4];
#pragma unroll
  for (int ni = 0; ni < 4; ++ni) bi[ni] = bias[nw + (ni << 4) + c16];

  if (p == 2) {  // V: store transposed [bh][d][t], vectorized half4 over t
#pragma unroll
    for (int mi = 0; mi < 4; ++mi) {
      int m = m0 + (wm << 6) + (mi << 4) + (rg << 2);
      int b = m >> 11, t0 = m & 2047;
#pragma unroll
      for (int ni = 0; ni < 4; ++ni) {
        half4 hv;
#pragma unroll
        for (int r = 0; r < 4; ++r) hv[r] = (_Float16)(acc[mi][ni][r] + bi[ni]);
        size_t base = ((size_t)(b * NH + head) * ND + (ni << 4) + c16) * NT + t0;
        *(half4*)&VT[base] = hv;
      }
    }
    return;
  }

  _Float16* Out = (p == 0) ? Qh : Kh;
  // Q scale: (1/sqrt(64)) * log2(e)  -> S from MFMA is directly in exp2 domain
  const float qscale = (p == 0) ? 0.18033688011112042f : 1.0f;

#pragma unroll
  for (int mi = 0; mi < 4; ++mi) {
#pragma unroll
    for (int r = 0; r < 4; ++r) {
      int m = m0 + (wm << 6) + (mi << 4) + (rg << 2) + r;
      int b = m >> 11, t = m & 2047;
      float v0 = acc[mi][0][r] + bi[0];
      float v1 = acc[mi][1][r] + bi[1];
      float v2 = acc[mi][2][r] + bi[2];
      float v3 = acc[mi][3][r] + bi[3];
      {  // RoPE on d<32: pair (d, d+16); trig from precomputed tables
        float cs = ct[(t << 4) + c16];
        float sn = st[(t << 4) + c16];
        float nx = v0 * cs - v1 * sn;
        v1 = v1 * cs + v0 * sn;
        v0 = nx;
      }
      size_t base = ((size_t)(b * NH + head) * NT + t) * ND;
      Out[base + 0 + c16]  = (_Float16)(v0 * qscale);
      Out[base + 16 + c16] = (_Float16)(v1 * qscale);
      Out[base + 32 + c16] = (_Float16)(v2 * qscale);
      Out[base + 48 + c16] = (_Float16)(v3 * qscale);
    }
  }
}

// ------ flash attention: 64-row tiles, 4 waves = 2 strips x (kv-lo, kv-hi) ------
// R19 config (best measured: 72.6us attn, zero spill at the exact 128-reg cap).
__global__ __launch_bounds__(256, 4) void k_attn(const _Float16* __restrict__ Qh,
                                                 const _Float16* __restrict__ Kh,
                                                 const _Float16* __restrict__ VT,
                                                 _Float16* __restrict__ Oh) {
  const int lin = blockIdx.x;            // 0..1023
  const int xcd = lin & 7;
  const int slot = lin >> 3;             // 0..127 within XCD
  const int rnd = slot >> 5;             // co-residency round 0..3
  const int pos = slot & 31;
  const int bh = (xcd << 2) | (pos & 3); // 4 bh per XCD -> K+V 2MB in per-XCD L2
  const int k8 = pos >> 2;               // 0..7
  const int t = (rnd == 0) ? (31 - k8) : (rnd == 1) ? k8
              : (rnd == 2) ? (23 - k8) : (8 + k8);   // sums to 62 across rounds

  const int tid = threadIdx.x, lane = tid & 63, wid = tid >> 6;  // wid 0..3
  const int s_strip = wid & 1, role = wid >> 1;
  const int q31 = lane & 31, hi = lane >> 5;
  const size_t hb = (size_t)bh * NT * ND;
  const _Float16* Qp = Qh + hb;
  const int b = bh >> 4, h = bh & 15;

  __shared__ float Osh[2][32][65];       // hi-role partial O per strip, +1 pad
  __shared__ float msh[2][32], lsh[2][32];

  const int q0w = (t << 6) + (s_strip << 5);  // this wave's 32 q-rows
  const int qg = q0w + q31;
  const int n = 2 * t + s_strip + 1;     // kv iterations (32 kv each) for this strip
  const int nh2 = (n + 1) >> 1;
  int it = role ? nh2 : 0;
  const int itend = role ? n : nh2;

  half8 qf[4];
#pragma unroll
  for (int c = 0; c < 4; ++c)
    qf[c] = *(const half8*)&Qp[(size_t)qg * ND + (c << 4) + (hi << 3)];

  f32x16 oacc0, oacc1;
#pragma unroll
  for (int r = 0; r < 16; ++r) { oacc0[r] = 0.f; oacc1[r] = 0.f; }
  float lacc[8];
#pragma unroll
  for (int r = 0; r < 8; ++r) lacc[r] = 0.f;
  float m = -INFINITY;

  half8 kA[4], vfr[4];

  // strength-reduced walking pointers (advance by constant strides per iter)
  const _Float16* kp = Kh + hb + (size_t)(((it << 5) + q31) * ND) + (hi << 3);
  const _Float16* vp = VT + hb + (size_t)q31 * NT + (it << 5) + (hi << 3);

#define LOADK() do {                                                            \
    kA[0] = *(const half8*)(kp);                                                \
    kA[1] = *(const half8*)(kp + 16);                                           \
    kA[2] = *(const half8*)(kp + 32);                                           \
    kA[3] = *(const half8*)(kp + 48);                                           \
  } while (0)

#define LOADV() do {                                                            \
    _Pragma("unroll")                                                           \
    for (int dh = 0; dh < 2; ++dh)                                              \
      _Pragma("unroll")                                                         \
      for (int ks = 0; ks < 2; ++ks)                                            \
        vfr[dh * 2 + ks] = *(const half8*)(vp + (size_t)(dh << 5) * NT + (ks << 4)); \
  } while (0)

#define BODY(ktc) do {                                                          \
    f32x16 s;                                                                   \
    _Pragma("unroll")                                                           \
    for (int r = 0; r < 16; ++r) s[r] = 0.f;                                    \
    __builtin_amdgcn_s_setprio(1);                                              \
    _Pragma("unroll")                                                           \
    for (int c = 0; c < 4; ++c)                                                 \
      s = __builtin_amdgcn_mfma_f32_32x32x16_f16(kA[c], qf[c], s, 0, 0, 0);     \
    __builtin_amdgcn_s_setprio(0);                                              \
    if ((ktc) + 31 > q0w) {  /* causal mask: only the strip's final iter */     \
      int rel = qg - (ktc) - (hi << 2);                                         \
      _Pragma("unroll")                                                         \
      for (int r = 0; r < 16; ++r) {                                            \
        int crow = (r & 3) + ((r >> 2) << 3);                                   \
        if (crow > rel) s[r] = -INFINITY;                                       \
      }                                                                         \
    }                                                                           \
    /* per-half local max tree; cross-half swap only when rescale triggers */   \
    float t8[8];                                                                \
    _Pragma("unroll")                                                           \
    for (int r = 0; r < 8; ++r) t8[r] = fmaxf(s[r], s[r + 8]);                  \
    _Pragma("unroll")                                                           \
    for (int r = 0; r < 4; ++r) t8[r] = fmaxf(t8[r], t8[r + 4]);                \
    float pml = fmaxf(fmaxf(t8[0], t8[1]), fmaxf(t8[2], t8[3]));                \
    if (!__all(pml <= m + 11.54f)) {  /* defer-max, THR=8*log2e */              \
      float pm = fmaxf(pml, __shfl_xor(pml, 32));                               \
      float mn = fmaxf(m, pm);                                                  \
      float corr = exp2f(m - mn);                                               \
      m = mn;                                                                   \
      _Pragma("unroll")                                                         \
      for (int r = 0; r < 16; ++r) { oacc0[r] *= corr; oacc1[r] *= corr; }      \
      _Pragma("unroll")                                                         \
      for (int r = 0; r < 8; ++r) lacc[r] *= corr;                              \
    }                                                                           \
    _Pragma("unroll")                                                           \
    for (int r = 0; r < 16; ++r) s[r] = exp2f(s[r] - m);                        \
    _Pragma("unroll")                                                           \
    for (int r = 0; r < 8; ++r) lacc[r] += s[r] + s[r + 8];                     \
    /* pack P; plswap(loWord, hiWord): r[0]->frag lo word, r[1]->hi */          \
    unsigned pw0 = __builtin_bit_cast(unsigned, __builtin_amdgcn_cvt_pkrtz(s[0], s[1]));   \
    unsigned pw1 = __builtin_bit_cast(unsigned, __builtin_amdgcn_cvt_pkrtz(s[2], s[3]));   \
    unsigned pw2 = __builtin_bit_cast(unsigned, __builtin_amdgcn_cvt_pkrtz(s[4], s[5]));   \
    unsigned pw3 = __builtin_bit_cast(unsigned, __builtin_amdgcn_cvt_pkrtz(s[6], s[7]));   \
    unsigned pw4 = __builtin_bit_cast(unsigned, __builtin_amdgcn_cvt_pkrtz(s[8], s[9]));   \
    unsigned pw5 = __builtin_bit_cast(unsigned, __builtin_amdgcn_cvt_pkrtz(s[10], s[11])); \
    unsigned pw6 = __builtin_bit_cast(unsigned, __builtin_amdgcn_cvt_pkrtz(s[12], s[13])); \
    unsigned pw7 = __builtin_bit_cast(unsigned, __builtin_amdgcn_cvt_pkrtz(s[14], s[15])); \
    uint2v rA0 = plswap(pw0, pw2);                                              \
    uint2v rA1 = plswap(pw1, pw3);                                              \
    uint2v rB0 = plswap(pw4, pw6);                                              \
    uint2v rB1 = plswap(pw5, pw7);                                              \
    uint4 ua, ub;                                                               \
    ua.x = rA0[0]; ua.y = rA1[0]; ua.z = rA0[1]; ua.w = rA1[1];                 \
    ub.x = rB0[0]; ub.y = rB1[0]; ub.z = rB0[1]; ub.w = rB1[1];                 \
    half8 pa0 = __builtin_bit_cast(half8, ua);                                  \
    half8 pa1 = __builtin_bit_cast(half8, ub);                                  \
    __builtin_amdgcn_s_setprio(1);                                              \
    oacc0 = __builtin_amdgcn_mfma_f32_32x32x16_f16(vfr[0], pa0, oacc0, 0, 0, 0); \
    oacc0 = __builtin_amdgcn_mfma_f32_32x32x16_f16(vfr[1], pa1, oacc0, 0, 0, 0); \
    oacc1 = __builtin_amdgcn_mfma_f32_32x32x16_f16(vfr[2], pa0, oacc1, 0, 0, 0); \
    oacc1 = __builtin_amdgcn_mfma_f32_32x32x16_f16(vfr[3], pa1, oacc1, 0, 0, 0); \
    __builtin_amdgcn_s_setprio(0);                                              \
  } while (0)

  // kv loop: K (consumed first) issued first, then V; walking pointers
  for (; it < itend; ++it) {
    LOADK();
    LOADV();
    BODY(it << 5);
    kp += 32 * ND;   // next 32 kv rows
    vp += 32;        // next 32 kv cols (t-major)
  }
#undef LOADK
#undef LOADV
#undef BODY

  // per-wave l reduction (in-lane tree + cross-half shfl)
  float l4[4];
#pragma unroll
  for (int r = 0; r < 4; ++r) l4[r] = lacc[r] + lacc[r + 4];
  float ls = (l4[0] + l4[1]) + (l4[2] + l4[3]);
  ls += __shfl_xor(ls, 32);

  // merge: hi-role waves publish partials, lo-role waves combine + store
  if (role == 1) {
    if (hi == 0) { msh[s_strip][q31] = m; lsh[s_strip][q31] = ls; }
#pragma unroll
    for (int g2 = 0; g2 < 4; ++g2)
#pragma unroll
      for (int r = 0; r < 4; ++r) {
        int d0 = (g2 << 3) + (hi << 2) + r;
        Osh[s_strip][q31][d0] = oacc0[(g2 << 2) + r];
        Osh[s_strip][q31][32 + d0] = oacc1[(g2 << 2) + r];
      }
  }
  __syncthreads();
  if (role == 0) {
    float m1 = msh[s_strip][q31], l1 = lsh[s_strip][q31];
    float M = fmaxf(m, m1);
    float c0 = exp2f(m - M);
    float c1 = exp2f(m1 - M);      // empty hi-half: m1=-inf -> c1=0
    float lt = c0 * ls + c1 * l1;
    float il = 1.f / lt;
    size_t obase = ((size_t)b * NT + qg) * NC + h * ND;
#pragma unroll
    for (int g2 = 0; g2 < 4; ++g2) {
      int d0 = (g2 << 3) + (hi << 2);
      half4 h4, h5;
#pragma unroll
      for (int r = 0; r < 4; ++r) {
        h4[r] = (_Float16)((c0 * oacc0[(g2 << 2) + r] + c1 * Osh[s_strip][q31][d0 + r]) * il);
        h5[r] = (_Float16)((c0 * oacc1[(g2 << 2) + r] + c1 * Osh[s_strip][q31][32 + d0 + r]) * il);
      }
      *(half4*)&Oh[obase + d0] = h4;
      *(half4*)&Oh[obase + 32 + d0] = h5;
    }
  }
}

// ---------------- output projection GEMM (fp32 out + bias) ----------------
__global__ __launch_bounds__(256, 2) void k_out(const _Float16* __restrict__ Oh,
                                                const _Float16* __restrict__ WoT,
                                                const float* __restrict__ bo,
                                                float* __restrict__ out) {
  __shared__ __align__(16) _Float16 As[128 * 64];
  __shared__ __align__(16) _Float16 Bs[128 * 64];
  f32x4 acc[4][4];
#pragma unroll
  for (int i = 0; i < 4; ++i)
#pragma unroll
    for (int j = 0; j < 4; ++j) acc[i][j] = (f32x4){0.f, 0.f, 0.f, 0.f};

  const int m0 = blockIdx.y * 128;
  const int n0 = blockIdx.x * 128;
  gemm_mainloop(Oh, WoT, m0, n0, As, Bs, acc);

  const int tid = threadIdx.x, lane = tid & 63, wid = tid >> 6;
  const int wm = wid >> 1, wn = wid & 1, c16 = lane & 15, rg = lane >> 4;
  float bi[4];
#pragma unroll
  for (int ni = 0; ni < 4; ++ni) bi[ni] = bo[n0 + (wn << 6) + (ni << 4) + c16];
#pragma unroll
  for (int mi = 0; mi < 4; ++mi) {
#pragma unroll
    for (int r = 0; r < 4; ++r) {
      int m = m0 + (wm << 6) + (mi << 4) + (rg << 2) + r;
#pragma unroll
      for (int ni = 0; ni < 4; ++ni) {
        int n = n0 + (wn << 6) + (ni << 4) + c16;
        out[(size_t)m * NC + n] = acc[mi][ni][r] + bi[ni];
      }
    }
  }
}

extern "C" void kernel_launch(void* const* d_in, const int* in_sizes, int n_in,
                              void* d_out, int out_size, void* d_ws, size_t ws_size,
                              hipStream_t stream) {
  const float* x  = (const float*)d_in[0];
  const float* Wq = (const float*)d_in[1];
  const float* bq = (const float*)d_in[2];
  const float* Wk = (const float*)d_in[3];
  const float* bk = (const float*)d_in[4];
  const float* Wv = (const float*)d_in[5];
  const float* bv = (const float*)d_in[6];
  const float* Wo = (const float*)d_in[7];
  const float* bo = (const float*)d_in[8];
  float* out = (float*)d_out;

  char* ws = (char*)d_ws;
  _Float16* xh = (_Float16*)ws;                       // 8 MB  [4096][1024]
  _Float16* WT = (_Float16*)(ws + (8ull << 20));      // 8 MB  [4][1024][1024] n-major
  _Float16* Qh = (_Float16*)(ws + (16ull << 20));     // 8 MB  [32][2048][64]
  _Float16* Kh = (_Float16*)(ws + (24ull << 20));     // 8 MB  [32][2048][64]
  _Float16* Vt = (_Float16*)(ws + (32ull << 20));     // 8 MB  [32][64][2048] (transposed)
  _Float16* Oh = (_Float16*)(ws + (40ull << 20));     // 8 MB  [4096][1024]
  // RoPE tables borrow the (currently dead) Oh region: consumed by k_qkv,
  // then k_attn overwrites Oh. 2048*16 f32 each = 128 KB + 128 KB.
  float* ct = (float*)(ws + (40ull << 20));
  float* st = (float*)(ws + (40ull << 20) + (2048 * 16 * 4));

  k_prep<<<dim3(32, 32, 6), dim3(32, 8), 0, stream>>>(x, Wq, Wk, Wv, Wo, xh, WT, ct, st);
  k_qkv<<<dim3(24, 32), 256, 0, stream>>>(xh, WT, bq, bk, bv, ct, st, Qh, Kh, Vt);
  k_attn<<<1024, 256, 0, stream>>>(Qh, Kh, Vt, Oh);
  k_out<<<dim3(8, 32), 256, 0, stream>>>(Oh, WT + (3ull << 20), bo, out);
}